// Round 2
// 556.787 us; speedup vs baseline: 1.0174x; 1.0174x over previous
//
#include <hip/hip_runtime.h>
#include <hip/hip_bf16.h>

#define NFEAT 256
#define NHID  128
#define NCLASS 40

typedef __attribute__((ext_vector_type(8))) short short8;
typedef __attribute__((ext_vector_type(4))) float float4v;

__device__ __forceinline__ unsigned short f2bf(float f) {
    union { float f; unsigned u; } v; v.f = f;
    unsigned r = v.u + 0x7fff + ((v.u >> 16) & 1);   // RNE
    return (unsigned short)(r >> 16);
}
__device__ __forceinline__ float bflo(unsigned u) { return __uint_as_float(u << 16); }
__device__ __forceinline__ float bfhi(unsigned u) { return __uint_as_float(u & 0xffff0000u); }
__device__ __forceinline__ unsigned packbf(float a, float b) {
    return (unsigned)f2bf(a) | ((unsigned)f2bf(b) << 16);
}

// async global->LDS, 16B per lane; LDS dest = wave-uniform base + lane*16
__device__ __forceinline__ void ld_g2l16(const unsigned short* gp, unsigned short* lp) {
    __builtin_amdgcn_global_load_lds((const __attribute__((address_space(1))) unsigned short*)gp,
                                     (__attribute__((address_space(3))) unsigned short*)lp,
                                     16, 0, 0);
}

#define TILE_E 4096   // edges per binning block

// ---- K1: per-block LDS histogram of row>>9 buckets -> few global atomics ----
// Also persists the per-block histogram (bh) so K3 doesn't re-histogram.
__global__ __launch_bounds__(256) void bin_hist(const int* __restrict__ rows,
                                                int* __restrict__ ghist,
                                                int* __restrict__ bh, int E, int nbuck) {
    __shared__ int hh[256];
    int t = threadIdx.x;
    hh[t] = 0;
    __syncthreads();
    int e0 = blockIdx.x * TILE_E;
    #pragma unroll
    for (int it = 0; it < TILE_E / 1024; ++it) {
        int base = e0 + (it * 256 + t) * 4;
        if (base + 3 < E) {
            int4 v = *reinterpret_cast<const int4*>(&rows[base]);
            atomicAdd(&hh[v.x >> 9], 1);
            atomicAdd(&hh[v.y >> 9], 1);
            atomicAdd(&hh[v.z >> 9], 1);
            atomicAdd(&hh[v.w >> 9], 1);
        } else {
            for (int k = 0; k < 4; ++k)
                if (base + k < E) atomicAdd(&hh[rows[base + k] >> 9], 1);
        }
    }
    __syncthreads();
    int h = hh[t];
    bh[blockIdx.x * 256 + t] = h;
    if (t < nbuck && h) atomicAdd(&ghist[t], h);
}

// ---- K2: scan bucket counts -> bases + cursors; row_ptr[N] = E ----
__global__ void scan_buckets(const int* __restrict__ ghist, int* __restrict__ gbase,
                             int* __restrict__ gcur, int* __restrict__ row_ptr,
                             int nbuck, int N, int E) {
    __shared__ int s[256];
    int t = threadIdx.x;
    int v = (t < nbuck) ? ghist[t] : 0;
    s[t] = v;
    __syncthreads();
    for (int off = 1; off < 256; off <<= 1) {
        int tmp = (t >= off) ? s[t - off] : 0;
        __syncthreads();
        s[t] += tmp;
        __syncthreads();
    }
    int excl = s[t] - v;
    if (t < nbuck) { gbase[t] = excl; gcur[t] = excl; }
    if (t == 0) { gbase[nbuck] = E; row_ptr[N] = E; }
}

// ---- K3: read persisted per-block hist, reserve chunks, scatter packed pairs ----
// packed entry: (row & 511) << 17 | col   (col < 2^17)
__global__ __launch_bounds__(256) void bin_scatter(const int* __restrict__ rows,
                                                   const int* __restrict__ cols,
                                                   const int* __restrict__ bh,
                                                   int* __restrict__ gcur,
                                                   unsigned* __restrict__ binned, int E, int nbuck) {
    __shared__ int lbase[256];
    __shared__ int lcur[256];
    int t = threadIdx.x;
    int h = bh[blockIdx.x * 256 + t];
    if (t < nbuck) {
        lbase[t] = h ? atomicAdd(&gcur[t], h) : 0;
        lcur[t] = 0;
    }
    __syncthreads();
    int e0 = blockIdx.x * TILE_E;
    #pragma unroll
    for (int it = 0; it < TILE_E / 1024; ++it) {
        int base = e0 + (it * 256 + t) * 4;
        if (base + 3 < E) {
            int4 r = *reinterpret_cast<const int4*>(&rows[base]);
            int4 c = *reinterpret_cast<const int4*>(&cols[base]);
            int b0 = r.x >> 9, b1 = r.y >> 9, b2 = r.z >> 9, b3 = r.w >> 9;
            int d0 = lbase[b0] + atomicAdd(&lcur[b0], 1);
            int d1 = lbase[b1] + atomicAdd(&lcur[b1], 1);
            int d2 = lbase[b2] + atomicAdd(&lcur[b2], 1);
            int d3 = lbase[b3] + atomicAdd(&lcur[b3], 1);
            binned[d0] = ((unsigned)(r.x & 511) << 17) | (unsigned)c.x;
            binned[d1] = ((unsigned)(r.y & 511) << 17) | (unsigned)c.y;
            binned[d2] = ((unsigned)(r.z & 511) << 17) | (unsigned)c.z;
            binned[d3] = ((unsigned)(r.w & 511) << 17) | (unsigned)c.w;
        } else {
            for (int k = 0; k < 4; ++k)
                if (base + k < E) {
                    int r = rows[base + k];
                    int b = r >> 9;
                    int dst = lbase[b] + atomicAdd(&lcur[b], 1);
                    binned[dst] = ((unsigned)(r & 511) << 17) | (unsigned)cols[base + k];
                }
        }
    }
}

// ---- K4: one block per 512-row window: degrees+scan -> row_ptr, inv_deg, CSR cols ----
__global__ __launch_bounds__(256) void fill_win(const unsigned* __restrict__ binned,
                                                const int* __restrict__ gbase,
                                                int* __restrict__ row_ptr,
                                                float* __restrict__ inv,
                                                int* __restrict__ csr_cols, int N) {
    __shared__ int h[512];
    __shared__ int ps[256];
    __shared__ int lcur[512];
    int t = threadIdx.x;
    int w = blockIdx.x;
    int r0 = w << 9;
    h[t] = 0; h[t + 256] = 0;
    __syncthreads();
    int beg = gbase[w], end = gbase[w + 1];
    for (int e = beg + t; e < end; e += 256)
        atomicAdd(&h[binned[e] >> 17], 1);
    __syncthreads();
    int pair = h[2 * t] + h[2 * t + 1];
    ps[t] = pair;
    __syncthreads();
    for (int off = 1; off < 256; off <<= 1) {
        int tmp = (t >= off) ? ps[t - off] : 0;
        __syncthreads();
        ps[t] += tmp;
        __syncthreads();
    }
    int base0 = beg + ps[t] - pair;
    int base1 = base0 + h[2 * t];
    int r_a = r0 + 2 * t, r_b = r0 + 2 * t + 1;
    if (r_a < N) { row_ptr[r_a] = base0; inv[r_a] = 1.0f / ((float)h[2 * t] + 1.0f); }
    if (r_b < N) { row_ptr[r_b] = base1; inv[r_b] = 1.0f / ((float)h[2 * t + 1] + 1.0f); }
    lcur[2 * t] = base0;
    lcur[2 * t + 1] = base1;
    __syncthreads();
    for (int e = beg + t; e < end; e += 256) {
        unsigned v = binned[e];
        int idx = atomicAdd(&lcur[v >> 17], 1);
        csr_cols[idx] = (int)(v & 0x1FFFFu);
    }
}

// ---------------- fused weight repack (W1, W2 -> K-panels; Wm -> padded bf16) ----------------
// Wp layout: [k0/32][o(256)][k(32)]
__global__ __launch_bounds__(256) void repack_all(const float* __restrict__ W1,
                                                  const float* __restrict__ W2,
                                                  const float* __restrict__ Wm,
                                                  unsigned short* __restrict__ Wp1,
                                                  unsigned short* __restrict__ Wp2,
                                                  unsigned short* __restrict__ Wb) {
    int b = blockIdx.x, t = threadIdx.x;
    if (b < 256) {                       // W1: o=b (0..255), k=t (0..255)
        float v = (b < 128) ? W1[b * 512 + t] : W1[(b - 128) * 512 + 256 + t];
        Wp1[(size_t)(t >> 5) * 256 * 32 + b * 32 + (t & 31)] = f2bf(v);
    } else if (b < 512) {                // W2: o=b-256 (0..255), k=t (0..127)
        int o = b - 256;
        if (t < 128) {
            float v = (o < 128) ? W2[o * 256 + t] : W2[(o - 128) * 256 + 128 + t];
            Wp2[(size_t)(t >> 5) * 256 * 32 + o * 32 + (t & 31)] = f2bf(v);
        }
    } else {                             // Wm: o=b-512 (0..47), k=t (0..127)
        int o = b - 512;
        if (t < 128) Wb[o * 128 + t] = (o < NCLASS) ? f2bf(Wm[o * 128 + t]) : 0;
    }
}

// ---------------- layer-1 GEMM: [PS|PN] = bf16(x[M x 256]) @ Wp1 ----------------
// BM=128, BN=256 (one pass over x), 8 waves; A via VGPR cvt, B via global_load_lds.
__global__ __launch_bounds__(512) void gemm1_mfma(const float* __restrict__ X,
                                                  const unsigned short* __restrict__ Wp,
                                                  unsigned short* __restrict__ PS,
                                                  unsigned short* __restrict__ PN,
                                                  int M) {
    __shared__ unsigned short sA[128 * 32];
    __shared__ unsigned short sB[256 * 32];
    const int t    = threadIdx.x;
    const int lane = t & 63;
    const int wave = t >> 6;              // 0..7
    const int m0 = blockIdx.x * 128;
    const int wm = (wave >> 2) * 64;      // 0 or 64
    const int wn = (wave & 3) * 64;       // 0,64,128,192

    const int r15 = lane & 15;
    const int k8  = (lane >> 4) * 8;
    const int arow = t >> 2;              // 0..127
    const int ac8  = (t & 3) * 8;
    const int brow = lane >> 2;           // 0..15
    const int bc8  = (lane & 3) * 8;

    float4v acc[4][4] = {{{0.f,0.f,0.f,0.f}}};
    const int gm = min(m0 + arow, M - 1);        // clamp: x is an input alloc
    const float* gA = X + (size_t)gm * 256 + ac8;

    for (int k0 = 0; k0 < 256; k0 += 32) {
        const unsigned short* pan = Wp + (size_t)(k0 >> 5) * 256 * 32;
        float4 v0 = *reinterpret_cast<const float4*>(gA + k0);
        float4 v1 = *reinterpret_cast<const float4*>(gA + k0 + 4);
        short8 av;
        av[0] = (short)f2bf(v0.x); av[1] = (short)f2bf(v0.y);
        av[2] = (short)f2bf(v0.z); av[3] = (short)f2bf(v0.w);
        av[4] = (short)f2bf(v1.x); av[5] = (short)f2bf(v1.y);
        av[6] = (short)f2bf(v1.z); av[7] = (short)f2bf(v1.w);
        *reinterpret_cast<short8*>(&sA[arow * 32 + ac8]) = av;
        #pragma unroll
        for (int it = 0; it < 2; ++it) {
            int slab = it * 128 + wave * 16;
            ld_g2l16(pan + (size_t)(slab + brow) * 32 + bc8, &sB[slab * 32]);
        }
        __syncthreads();

        short8 aF[4], bF[4];
        #pragma unroll
        for (int i = 0; i < 4; ++i)
            aF[i] = *reinterpret_cast<const short8*>(&sA[(wm + i * 16 + r15) * 32 + k8]);
        #pragma unroll
        for (int j = 0; j < 4; ++j)
            bF[j] = *reinterpret_cast<const short8*>(&sB[(wn + j * 16 + r15) * 32 + k8]);
        #pragma unroll
        for (int i = 0; i < 4; ++i)
            #pragma unroll
            for (int j = 0; j < 4; ++j)
                acc[i][j] = __builtin_amdgcn_mfma_f32_16x16x32_bf16(aF[i], bF[j], acc[i][j], 0, 0, 0);
        __syncthreads();
    }

    #pragma unroll
    for (int i = 0; i < 4; ++i) {
        #pragma unroll
        for (int r = 0; r < 4; ++r) {
            int row = m0 + wm + i * 16 + (lane >> 4) * 4 + r;
            #pragma unroll
            for (int j = 0; j < 4; ++j) {
                float v  = acc[i][j][r];
                float vn = __shfl_xor(v, 1);
                int cN = wn + j * 16 + r15;
                unsigned short* out = (cN < 128) ? PS : PN;
                if (row < M && !(r15 & 1))
                    *reinterpret_cast<unsigned*>(&out[(size_t)row * 128 + (cN & 127)]) = packbf(v, vn);
            }
        }
    }
}

// ---------------- layer-2 GEMM: [PS|PN] = H[M x 128] @ Wp2, async A+B staging ----------------
// BM=128, BN=256 (one pass over H). A-tail of last M-block overreads into adjacent ws — safe.
__global__ __launch_bounds__(512) void gemm2_mfma(const unsigned short* __restrict__ H,
                                                  const unsigned short* __restrict__ Wp,
                                                  unsigned short* __restrict__ PS,
                                                  unsigned short* __restrict__ PN,
                                                  int M) {
    __shared__ unsigned short sA[128 * 32];
    __shared__ unsigned short sB[256 * 32];
    const int t    = threadIdx.x;
    const int lane = t & 63;
    const int wave = t >> 6;
    const int m0 = blockIdx.x * 128;
    const int wm = (wave >> 2) * 64;
    const int wn = (wave & 3) * 64;

    const int r15 = lane & 15;
    const int k8  = (lane >> 4) * 8;
    const int brow = lane >> 2;
    const int bc8  = (lane & 3) * 8;

    float4v acc[4][4] = {{{0.f,0.f,0.f,0.f}}};

    for (int k0 = 0; k0 < 128; k0 += 32) {
        const unsigned short* pan = Wp + (size_t)(k0 >> 5) * 256 * 32;
        int slabA = wave * 16;
        ld_g2l16(H + (size_t)(m0 + slabA + brow) * 128 + k0 + bc8, &sA[slabA * 32]);
        #pragma unroll
        for (int it = 0; it < 2; ++it) {
            int slab = it * 128 + wave * 16;
            ld_g2l16(pan + (size_t)(slab + brow) * 32 + bc8, &sB[slab * 32]);
        }
        __syncthreads();

        short8 aF[4], bF[4];
        #pragma unroll
        for (int i = 0; i < 4; ++i)
            aF[i] = *reinterpret_cast<const short8*>(&sA[(wm + i * 16 + r15) * 32 + k8]);
        #pragma unroll
        for (int j = 0; j < 4; ++j)
            bF[j] = *reinterpret_cast<const short8*>(&sB[(wn + j * 16 + r15) * 32 + k8]);
        #pragma unroll
        for (int i = 0; i < 4; ++i)
            #pragma unroll
            for (int j = 0; j < 4; ++j)
                acc[i][j] = __builtin_amdgcn_mfma_f32_16x16x32_bf16(aF[i], bF[j], acc[i][j], 0, 0, 0);
        __syncthreads();
    }

    #pragma unroll
    for (int i = 0; i < 4; ++i) {
        #pragma unroll
        for (int r = 0; r < 4; ++r) {
            int row = m0 + wm + i * 16 + (lane >> 4) * 4 + r;
            #pragma unroll
            for (int j = 0; j < 4; ++j) {
                float v  = acc[i][j][r];
                float vn = __shfl_xor(v, 1);
                int cN = wn + j * 16 + r15;
                unsigned short* out = (cN < 128) ? PS : PN;
                if (row < M && !(r15 & 1))
                    *reinterpret_cast<unsigned*>(&out[(size_t)row * 128 + (cN & 127)]) = packbf(v, vn);
            }
        }
    }
}

// ---------------- gather-aggregate + combine + relu: one wave per node ----------------
// PN random-gather working set = 25.6MB; PS/invdeg loads hoisted above the edge loop
// so their latency overlaps the gather chain instead of serializing at the tail.
__global__ __launch_bounds__(256) void gather_combine(const unsigned short* __restrict__ PS,
                                                      const unsigned short* __restrict__ PN,
                                                      const int* __restrict__ row_ptr,
                                                      const int* __restrict__ csr_cols,
                                                      const float* __restrict__ invdeg,
                                                      unsigned short* __restrict__ H, int N) {
    int node = (blockIdx.x * blockDim.x + threadIdx.x) >> 6;
    if (node >= N) return;
    int lane = threadIdx.x & 63;
    int grp  = lane >> 4;
    int l16  = lane & 15;
    int beg = row_ptr[node], end = row_ptr[node + 1];

    float id = 0.f;
    uint4 us = {0u, 0u, 0u, 0u};
    if (grp == 0) {
        id = invdeg[node];
        us = *reinterpret_cast<const uint4*>(&PS[(size_t)node * 128 + l16 * 8]);
    }

    float a0=0,a1=0,a2=0,a3=0,a4=0,a5=0,a6=0,a7=0;
    int p0 = beg + grp;
    for (; p0 + 12 < end; p0 += 16) {
        int cA = csr_cols[p0];
        int cB = csr_cols[p0 + 4];
        int cC = csr_cols[p0 + 8];
        int cD = csr_cols[p0 + 12];
        uint4 uA = *reinterpret_cast<const uint4*>(&PN[(size_t)cA * 128 + l16 * 8]);
        uint4 uB = *reinterpret_cast<const uint4*>(&PN[(size_t)cB * 128 + l16 * 8]);
        uint4 uC = *reinterpret_cast<const uint4*>(&PN[(size_t)cC * 128 + l16 * 8]);
        uint4 uD = *reinterpret_cast<const uint4*>(&PN[(size_t)cD * 128 + l16 * 8]);
        a0 += bflo(uA.x) + bflo(uB.x) + bflo(uC.x) + bflo(uD.x);
        a1 += bfhi(uA.x) + bfhi(uB.x) + bfhi(uC.x) + bfhi(uD.x);
        a2 += bflo(uA.y) + bflo(uB.y) + bflo(uC.y) + bflo(uD.y);
        a3 += bfhi(uA.y) + bfhi(uB.y) + bfhi(uC.y) + bfhi(uD.y);
        a4 += bflo(uA.z) + bflo(uB.z) + bflo(uC.z) + bflo(uD.z);
        a5 += bfhi(uA.z) + bfhi(uB.z) + bfhi(uC.z) + bfhi(uD.z);
        a6 += bflo(uA.w) + bflo(uB.w) + bflo(uC.w) + bflo(uD.w);
        a7 += bfhi(uA.w) + bfhi(uB.w) + bfhi(uC.w) + bfhi(uD.w);
    }
    for (; p0 < end; p0 += 4) {
        int c = csr_cols[p0];
        uint4 u = *reinterpret_cast<const uint4*>(&PN[(size_t)c * 128 + l16 * 8]);
        a0 += bflo(u.x); a1 += bfhi(u.x);
        a2 += bflo(u.y); a3 += bfhi(u.y);
        a4 += bflo(u.z); a5 += bfhi(u.z);
        a6 += bflo(u.w); a7 += bfhi(u.w);
    }
    a0 += __shfl_xor(a0, 16); a1 += __shfl_xor(a1, 16);
    a2 += __shfl_xor(a2, 16); a3 += __shfl_xor(a3, 16);
    a4 += __shfl_xor(a4, 16); a5 += __shfl_xor(a5, 16);
    a6 += __shfl_xor(a6, 16); a7 += __shfl_xor(a7, 16);
    a0 += __shfl_xor(a0, 32); a1 += __shfl_xor(a1, 32);
    a2 += __shfl_xor(a2, 32); a3 += __shfl_xor(a3, 32);
    a4 += __shfl_xor(a4, 32); a5 += __shfl_xor(a5, 32);
    a6 += __shfl_xor(a6, 32); a7 += __shfl_xor(a7, 32);

    if (grp == 0) {
        float h0 = fmaxf(fmaf(a0, id, bflo(us.x)), 0.f);
        float h1 = fmaxf(fmaf(a1, id, bfhi(us.x)), 0.f);
        float h2 = fmaxf(fmaf(a2, id, bflo(us.y)), 0.f);
        float h3 = fmaxf(fmaf(a3, id, bfhi(us.y)), 0.f);
        float h4 = fmaxf(fmaf(a4, id, bflo(us.z)), 0.f);
        float h5 = fmaxf(fmaf(a5, id, bfhi(us.z)), 0.f);
        float h6 = fmaxf(fmaf(a6, id, bflo(us.w)), 0.f);
        float h7 = fmaxf(fmaf(a7, id, bfhi(us.w)), 0.f);
        uint4 o;
        o.x = packbf(h0, h1); o.y = packbf(h2, h3);
        o.z = packbf(h4, h5); o.w = packbf(h6, h7);
        *reinterpret_cast<uint4*>(&H[(size_t)node * 128 + l16 * 8]) = o;
    }
}

// ---------------- MFMA head: logits = H @ Wb^T (+bias), fused log_softmax ----------------
__global__ __launch_bounds__(256) void mlp_head_mfma(const unsigned short* __restrict__ H,
                                                     const unsigned short* __restrict__ Wb,
                                                     const float* __restrict__ bm,
                                                     float* __restrict__ out, int N) {
    __shared__ unsigned short sW[48 * 128];   // 12 KB
    int t = threadIdx.x;
    for (int i = t; i < 48 * 128 / 2; i += 256)
        ((unsigned*)sW)[i] = ((const unsigned*)Wb)[i];
    __syncthreads();

    const int wave = t >> 6, lane = t & 63;
    const int m0 = blockIdx.x * 64 + wave * 16;
    if (m0 >= N) return;
    const int r15 = lane & 15;
    const int k8  = (lane >> 4) * 8;
    const int arow = min(m0 + r15, N - 1);

    float4v acc[3] = {{0.f,0.f,0.f,0.f},{0.f,0.f,0.f,0.f},{0.f,0.f,0.f,0.f}};
    #pragma unroll
    for (int k0 = 0; k0 < 128; k0 += 32) {
        short8 a = *reinterpret_cast<const short8*>(&H[(size_t)arow * 128 + k0 + k8]);
        #pragma unroll
        for (int f = 0; f < 3; ++f) {
            short8 b = *reinterpret_cast<const short8*>(&sW[(f * 16 + r15) * 128 + k0 + k8]);
            acc[f] = __builtin_amdgcn_mfma_f32_16x16x32_bf16(a, b, acc[f], 0, 0, 0);
        }
    }

    float bias[3]; bool cv[3];
    #pragma unroll
    for (int f = 0; f < 3; ++f) {
        int c = f * 16 + r15;
        cv[f] = (c < NCLASS);
        bias[f] = cv[f] ? bm[c] : 0.f;
    }
    #pragma unroll
    for (int r = 0; r < 4; ++r) {
        int node = m0 + (lane >> 4) * 4 + r;
        float lg[3];
        float m = -1e30f;
        #pragma unroll
        for (int f = 0; f < 3; ++f) {
            lg[f] = cv[f] ? (acc[f][r] + bias[f]) : -1e30f;
            m = fmaxf(m, lg[f]);
        }
        m = fmaxf(m, __shfl_xor(m, 1));
        m = fmaxf(m, __shfl_xor(m, 2));
        m = fmaxf(m, __shfl_xor(m, 4));
        m = fmaxf(m, __shfl_xor(m, 8));
        float s = 0.f;
        #pragma unroll
        for (int f = 0; f < 3; ++f) s += cv[f] ? __expf(lg[f] - m) : 0.f;
        s += __shfl_xor(s, 1);
        s += __shfl_xor(s, 2);
        s += __shfl_xor(s, 4);
        s += __shfl_xor(s, 8);
        float ls = __logf(s);
        if (node < N) {
            #pragma unroll
            for (int f = 0; f < 3; ++f)
                if (cv[f]) out[(size_t)node * NCLASS + f * 16 + r15] = lg[f] - m - ls;
        }
    }
}

extern "C" void kernel_launch(void* const* d_in, const int* in_sizes, int n_in,
                              void* d_out, int out_size, void* d_ws, size_t ws_size,
                              hipStream_t stream) {
    const float* x    = (const float*)d_in[0];
    const float* W1   = (const float*)d_in[1];
    const float* W2   = (const float*)d_in[2];
    const float* mlpW = (const float*)d_in[3];
    const float* mlpb = (const float*)d_in[4];
    const int*   rows = (const int*)d_in[5];
    const int*   cols = (const int*)d_in[6];

    const int N = in_sizes[0] / NFEAT;   // 100000
    const int E = in_sizes[5];           // 3200000

    char* ws = (char*)d_ws;
    size_t off = 0;
    auto alloc = [&](size_t bytes) -> void* {
        void* p = ws + off;
        off = (off + bytes + 255) & ~(size_t)255;
        return p;
    };
    unsigned short* PS  = (unsigned short*)alloc((size_t)N * 128 * 2);  // self-projection
    unsigned short* PN  = (unsigned short*)alloc((size_t)N * 128 * 2);  // neigh-projection
    unsigned short* H   = (unsigned short*)alloc((size_t)N * 128 * 2);  // hidden
    float* INV    = (float*)alloc((size_t)N * 4);
    int*   ROWP   = (int*)  alloc((size_t)(N + 1) * 4);
    int*   CSRC   = (int*)  alloc((size_t)E * 4);
    unsigned* BINNED = (unsigned*)alloc((size_t)E * 4);
    int*   GHIST  = (int*)  alloc((size_t)256 * 4);
    int*   GBASE  = (int*)  alloc((size_t)257 * 4);
    int*   GCUR   = (int*)  alloc((size_t)256 * 4);
    unsigned short* Wp1 = (unsigned short*)alloc((size_t)256 * 256 * 2);
    unsigned short* Wp2 = (unsigned short*)alloc((size_t)128 * 256 * 2);
    unsigned short* Wb  = (unsigned short*)alloc((size_t)48 * 128 * 2);

    const int nbuck = (N + 511) >> 9;              // 196
    const int nblk  = (E + TILE_E - 1) / TILE_E;   // 782

    // Per-block histograms from K1, consumed by K3. Aliased into CSRC's space:
    // CSRC is only written by fill_win (K4), which runs after bin_scatter (K3)
    // has finished reading BH. nblk*256*4 = 800KB <= E*4 = 12.8MB.
    int* BH = (int*)CSRC;

    // ---- CSR build via LDS-histogram binning (also produces row_ptr + inv_deg) ----
    hipMemsetAsync(GHIST, 0, 256 * 4, stream);
    bin_hist<<<nblk, 256, 0, stream>>>(rows, GHIST, BH, E, nbuck);
    scan_buckets<<<1, 256, 0, stream>>>(GHIST, GBASE, GCUR, ROWP, nbuck, N, E);
    bin_scatter<<<nblk, 256, 0, stream>>>(rows, cols, BH, GCUR, BINNED, E, nbuck);
    fill_win<<<nbuck, 256, 0, stream>>>(BINNED, GBASE, ROWP, INV, CSRC, N);

    // ---- weight prep ----
    repack_all<<<560, 256, 0, stream>>>(W1, W2, mlpW, Wp1, Wp2, Wb);

    const int mblocks = (N + 127) / 128;   // 782
    const int gblocks = (int)(((long long)N * 64 + 255) / 256);

    // ---- layer 1 (reads fp32 x ONCE: BN=256 covers both PS and PN halves) ----
    gemm1_mfma<<<mblocks, 512, 0, stream>>>(x, Wp1, PS, PN, N);
    gather_combine<<<gblocks, 256, 0, stream>>>(PS, PN, ROWP, CSRC, INV, H, N);

    // ---- layer 2 ----
    gemm2_mfma<<<mblocks, 512, 0, stream>>>(H, Wp2, PS, PN, N);
    gather_combine<<<gblocks, 256, 0, stream>>>(PS, PN, ROWP, CSRC, INV, H, N);

    // ---- head ----
    mlp_head_mfma<<<(N + 63) / 64, 256, 0, stream>>>(H, Wb, mlpb, (float*)d_out, N);
}

// Round 3
// 475.577 us; speedup vs baseline: 1.1911x; 1.1708x over previous
//
#include <hip/hip_runtime.h>
#include <hip/hip_bf16.h>

#define NFEAT 256
#define NHID  128
#define NCLASS 40

typedef __attribute__((ext_vector_type(8))) short short8;
typedef __attribute__((ext_vector_type(4))) float float4v;

__device__ __forceinline__ unsigned short f2bf(float f) {
    union { float f; unsigned u; } v; v.f = f;
    unsigned r = v.u + 0x7fff + ((v.u >> 16) & 1);   // RNE
    return (unsigned short)(r >> 16);
}
__device__ __forceinline__ float bflo(unsigned u) { return __uint_as_float(u << 16); }
__device__ __forceinline__ float bfhi(unsigned u) { return __uint_as_float(u & 0xffff0000u); }
__device__ __forceinline__ unsigned packbf(float a, float b) {
    return (unsigned)f2bf(a) | ((unsigned)f2bf(b) << 16);
}

// async global->LDS, 16B per lane; LDS dest = wave-uniform base + lane*16
__device__ __forceinline__ void ld_g2l16(const unsigned short* gp, unsigned short* lp) {
    __builtin_amdgcn_global_load_lds((const __attribute__((address_space(1))) unsigned short*)gp,
                                     (__attribute__((address_space(3))) unsigned short*)lp,
                                     16, 0, 0);
}

#define TILE_E 4096   // edges per binning block

// ---- K1: per-block LDS histogram of row>>9 buckets -> few global atomics ----
// Also persists the per-block histogram (bh) so K3 doesn't re-histogram.
__global__ __launch_bounds__(256) void bin_hist(const int* __restrict__ rows,
                                                int* __restrict__ ghist,
                                                int* __restrict__ bh, int E, int nbuck) {
    __shared__ int hh[256];
    int t = threadIdx.x;
    hh[t] = 0;
    __syncthreads();
    int e0 = blockIdx.x * TILE_E;
    #pragma unroll
    for (int it = 0; it < TILE_E / 1024; ++it) {
        int base = e0 + (it * 256 + t) * 4;
        if (base + 3 < E) {
            int4 v = *reinterpret_cast<const int4*>(&rows[base]);
            atomicAdd(&hh[v.x >> 9], 1);
            atomicAdd(&hh[v.y >> 9], 1);
            atomicAdd(&hh[v.z >> 9], 1);
            atomicAdd(&hh[v.w >> 9], 1);
        } else {
            for (int k = 0; k < 4; ++k)
                if (base + k < E) atomicAdd(&hh[rows[base + k] >> 9], 1);
        }
    }
    __syncthreads();
    int h = hh[t];
    bh[blockIdx.x * 256 + t] = h;
    if (t < nbuck && h) atomicAdd(&ghist[t], h);
}

// ---- K2: scan bucket counts -> bases + cursors; row_ptr[N] = E ----
__global__ void scan_buckets(const int* __restrict__ ghist, int* __restrict__ gbase,
                             int* __restrict__ gcur, int* __restrict__ row_ptr,
                             int nbuck, int N, int E) {
    __shared__ int s[256];
    int t = threadIdx.x;
    int v = (t < nbuck) ? ghist[t] : 0;
    s[t] = v;
    __syncthreads();
    for (int off = 1; off < 256; off <<= 1) {
        int tmp = (t >= off) ? s[t - off] : 0;
        __syncthreads();
        s[t] += tmp;
        __syncthreads();
    }
    int excl = s[t] - v;
    if (t < nbuck) { gbase[t] = excl; gcur[t] = excl; }
    if (t == 0) { gbase[nbuck] = E; row_ptr[N] = E; }
}

// ---- K3: read persisted per-block hist, reserve chunks, scatter packed pairs ----
// packed entry: (row & 511) << 17 | col   (col < 2^17)
__global__ __launch_bounds__(256) void bin_scatter(const int* __restrict__ rows,
                                                   const int* __restrict__ cols,
                                                   const int* __restrict__ bh,
                                                   int* __restrict__ gcur,
                                                   unsigned* __restrict__ binned, int E, int nbuck) {
    __shared__ int lbase[256];
    __shared__ int lcur[256];
    int t = threadIdx.x;
    int h = bh[blockIdx.x * 256 + t];
    if (t < nbuck) {
        lbase[t] = h ? atomicAdd(&gcur[t], h) : 0;
        lcur[t] = 0;
    }
    __syncthreads();
    int e0 = blockIdx.x * TILE_E;
    #pragma unroll
    for (int it = 0; it < TILE_E / 1024; ++it) {
        int base = e0 + (it * 256 + t) * 4;
        if (base + 3 < E) {
            int4 r = *reinterpret_cast<const int4*>(&rows[base]);
            int4 c = *reinterpret_cast<const int4*>(&cols[base]);
            int b0 = r.x >> 9, b1 = r.y >> 9, b2 = r.z >> 9, b3 = r.w >> 9;
            int d0 = lbase[b0] + atomicAdd(&lcur[b0], 1);
            int d1 = lbase[b1] + atomicAdd(&lcur[b1], 1);
            int d2 = lbase[b2] + atomicAdd(&lcur[b2], 1);
            int d3 = lbase[b3] + atomicAdd(&lcur[b3], 1);
            binned[d0] = ((unsigned)(r.x & 511) << 17) | (unsigned)c.x;
            binned[d1] = ((unsigned)(r.y & 511) << 17) | (unsigned)c.y;
            binned[d2] = ((unsigned)(r.z & 511) << 17) | (unsigned)c.z;
            binned[d3] = ((unsigned)(r.w & 511) << 17) | (unsigned)c.w;
        } else {
            for (int k = 0; k < 4; ++k)
                if (base + k < E) {
                    int r = rows[base + k];
                    int b = r >> 9;
                    int dst = lbase[b] + atomicAdd(&lcur[b], 1);
                    binned[dst] = ((unsigned)(r & 511) << 17) | (unsigned)cols[base + k];
                }
        }
    }
}

// ---- K4: one block per 512-row window: degrees+scan -> row_ptr, inv_deg, CSR cols ----
__global__ __launch_bounds__(256) void fill_win(const unsigned* __restrict__ binned,
                                                const int* __restrict__ gbase,
                                                int* __restrict__ row_ptr,
                                                float* __restrict__ inv,
                                                int* __restrict__ csr_cols, int N) {
    __shared__ int h[512];
    __shared__ int ps[256];
    __shared__ int lcur[512];
    int t = threadIdx.x;
    int w = blockIdx.x;
    int r0 = w << 9;
    h[t] = 0; h[t + 256] = 0;
    __syncthreads();
    int beg = gbase[w], end = gbase[w + 1];
    for (int e = beg + t; e < end; e += 256)
        atomicAdd(&h[binned[e] >> 17], 1);
    __syncthreads();
    int pair = h[2 * t] + h[2 * t + 1];
    ps[t] = pair;
    __syncthreads();
    for (int off = 1; off < 256; off <<= 1) {
        int tmp = (t >= off) ? ps[t - off] : 0;
        __syncthreads();
        ps[t] += tmp;
        __syncthreads();
    }
    int base0 = beg + ps[t] - pair;
    int base1 = base0 + h[2 * t];
    int r_a = r0 + 2 * t, r_b = r0 + 2 * t + 1;
    if (r_a < N) { row_ptr[r_a] = base0; inv[r_a] = 1.0f / ((float)h[2 * t] + 1.0f); }
    if (r_b < N) { row_ptr[r_b] = base1; inv[r_b] = 1.0f / ((float)h[2 * t + 1] + 1.0f); }
    lcur[2 * t] = base0;
    lcur[2 * t + 1] = base1;
    __syncthreads();
    for (int e = beg + t; e < end; e += 256) {
        unsigned v = binned[e];
        int idx = atomicAdd(&lcur[v >> 17], 1);
        csr_cols[idx] = (int)(v & 0x1FFFFu);
    }
}

// ---------------- fused weight repack (W1, W2 -> K-panels; Wm -> padded bf16) ----------------
// Wp layout: [k0/32][o(256)][k(32)]
__global__ __launch_bounds__(256) void repack_all(const float* __restrict__ W1,
                                                  const float* __restrict__ W2,
                                                  const float* __restrict__ Wm,
                                                  unsigned short* __restrict__ Wp1,
                                                  unsigned short* __restrict__ Wp2,
                                                  unsigned short* __restrict__ Wb) {
    int b = blockIdx.x, t = threadIdx.x;
    if (b < 256) {                       // W1: o=b (0..255), k=t (0..255)
        float v = (b < 128) ? W1[b * 512 + t] : W1[(b - 128) * 512 + 256 + t];
        Wp1[(size_t)(t >> 5) * 256 * 32 + b * 32 + (t & 31)] = f2bf(v);
    } else if (b < 512) {                // W2: o=b-256 (0..255), k=t (0..127)
        int o = b - 256;
        if (t < 128) {
            float v = (o < 128) ? W2[o * 256 + t] : W2[(o - 128) * 256 + 128 + t];
            Wp2[(size_t)(t >> 5) * 256 * 32 + o * 32 + (t & 31)] = f2bf(v);
        }
    } else {                             // Wm: o=b-512 (0..47), k=t (0..127)
        int o = b - 512;
        if (t < 128) Wb[o * 128 + t] = (o < NCLASS) ? f2bf(Wm[o * 128 + t]) : 0;
    }
}

// ---------------- layer-1 GEMM: [PS|PN8] = bf16(x[M x 256]) @ Wp1 ----------------
// BM=128, BN=256 (one pass over x), 8 waves; A via VGPR cvt, B via global_load_lds.
// PS (self half) stored bf16; PN (neigh half) stored fp8 e4m3 via HW cvt (halves gather bytes).
__global__ __launch_bounds__(512) void gemm1_mfma(const float* __restrict__ X,
                                                  const unsigned short* __restrict__ Wp,
                                                  unsigned short* __restrict__ PS,
                                                  unsigned char* __restrict__ PN8,
                                                  int M) {
    __shared__ unsigned short sA[128 * 32];
    __shared__ unsigned short sB[256 * 32];
    const int t    = threadIdx.x;
    const int lane = t & 63;
    const int wave = t >> 6;              // 0..7
    const int m0 = blockIdx.x * 128;
    const int wm = (wave >> 2) * 64;      // 0 or 64
    const int wn = (wave & 3) * 64;       // 0,64,128,192

    const int r15 = lane & 15;
    const int k8  = (lane >> 4) * 8;
    const int arow = t >> 2;              // 0..127
    const int ac8  = (t & 3) * 8;
    const int brow = lane >> 2;           // 0..15
    const int bc8  = (lane & 3) * 8;

    float4v acc[4][4] = {{{0.f,0.f,0.f,0.f}}};
    const int gm = min(m0 + arow, M - 1);        // clamp: x is an input alloc
    const float* gA = X + (size_t)gm * 256 + ac8;

    for (int k0 = 0; k0 < 256; k0 += 32) {
        const unsigned short* pan = Wp + (size_t)(k0 >> 5) * 256 * 32;
        float4 v0 = *reinterpret_cast<const float4*>(gA + k0);
        float4 v1 = *reinterpret_cast<const float4*>(gA + k0 + 4);
        short8 av;
        av[0] = (short)f2bf(v0.x); av[1] = (short)f2bf(v0.y);
        av[2] = (short)f2bf(v0.z); av[3] = (short)f2bf(v0.w);
        av[4] = (short)f2bf(v1.x); av[5] = (short)f2bf(v1.y);
        av[6] = (short)f2bf(v1.z); av[7] = (short)f2bf(v1.w);
        *reinterpret_cast<short8*>(&sA[arow * 32 + ac8]) = av;
        #pragma unroll
        for (int it = 0; it < 2; ++it) {
            int slab = it * 128 + wave * 16;
            ld_g2l16(pan + (size_t)(slab + brow) * 32 + bc8, &sB[slab * 32]);
        }
        __syncthreads();

        short8 aF[4], bF[4];
        #pragma unroll
        for (int i = 0; i < 4; ++i)
            aF[i] = *reinterpret_cast<const short8*>(&sA[(wm + i * 16 + r15) * 32 + k8]);
        #pragma unroll
        for (int j = 0; j < 4; ++j)
            bF[j] = *reinterpret_cast<const short8*>(&sB[(wn + j * 16 + r15) * 32 + k8]);
        #pragma unroll
        for (int i = 0; i < 4; ++i)
            #pragma unroll
            for (int j = 0; j < 4; ++j)
                acc[i][j] = __builtin_amdgcn_mfma_f32_16x16x32_bf16(aF[i], bF[j], acc[i][j], 0, 0, 0);
        __syncthreads();
    }

    #pragma unroll
    for (int i = 0; i < 4; ++i) {
        #pragma unroll
        for (int r = 0; r < 4; ++r) {
            int row = m0 + wm + i * 16 + (lane >> 4) * 4 + r;
            #pragma unroll
            for (int j = 0; j < 4; ++j) {
                float v  = acc[i][j][r];
                float vn = __shfl_xor(v, 1);
                int cN = wn + j * 16 + r15;
                if (row < M && !(r15 & 1)) {
                    if (cN < 128) {
                        *reinterpret_cast<unsigned*>(&PS[(size_t)row * 128 + cN]) = packbf(v, vn);
                    } else {
                        unsigned p8 = __builtin_amdgcn_cvt_pk_fp8_f32(v, vn, 0u, false);
                        *reinterpret_cast<unsigned short*>(&PN8[(size_t)row * 128 + (cN - 128)]) =
                            (unsigned short)p8;
                    }
                }
            }
        }
    }
}

// ---------------- layer-2 GEMM: [PS|PN8] = H[M x 128] @ Wp2, async A+B staging ----------------
// BM=128, BN=256 (one pass over H). A-tail of last M-block overreads into adjacent ws — safe.
__global__ __launch_bounds__(512) void gemm2_mfma(const unsigned short* __restrict__ H,
                                                  const unsigned short* __restrict__ Wp,
                                                  unsigned short* __restrict__ PS,
                                                  unsigned char* __restrict__ PN8,
                                                  int M) {
    __shared__ unsigned short sA[128 * 32];
    __shared__ unsigned short sB[256 * 32];
    const int t    = threadIdx.x;
    const int lane = t & 63;
    const int wave = t >> 6;
    const int m0 = blockIdx.x * 128;
    const int wm = (wave >> 2) * 64;
    const int wn = (wave & 3) * 64;

    const int r15 = lane & 15;
    const int k8  = (lane >> 4) * 8;
    const int brow = lane >> 2;
    const int bc8  = (lane & 3) * 8;

    float4v acc[4][4] = {{{0.f,0.f,0.f,0.f}}};

    for (int k0 = 0; k0 < 128; k0 += 32) {
        const unsigned short* pan = Wp + (size_t)(k0 >> 5) * 256 * 32;
        int slabA = wave * 16;
        ld_g2l16(H + (size_t)(m0 + slabA + brow) * 128 + k0 + bc8, &sA[slabA * 32]);
        #pragma unroll
        for (int it = 0; it < 2; ++it) {
            int slab = it * 128 + wave * 16;
            ld_g2l16(pan + (size_t)(slab + brow) * 32 + bc8, &sB[slab * 32]);
        }
        __syncthreads();

        short8 aF[4], bF[4];
        #pragma unroll
        for (int i = 0; i < 4; ++i)
            aF[i] = *reinterpret_cast<const short8*>(&sA[(wm + i * 16 + r15) * 32 + k8]);
        #pragma unroll
        for (int j = 0; j < 4; ++j)
            bF[j] = *reinterpret_cast<const short8*>(&sB[(wn + j * 16 + r15) * 32 + k8]);
        #pragma unroll
        for (int i = 0; i < 4; ++i)
            #pragma unroll
            for (int j = 0; j < 4; ++j)
                acc[i][j] = __builtin_amdgcn_mfma_f32_16x16x32_bf16(aF[i], bF[j], acc[i][j], 0, 0, 0);
        __syncthreads();
    }

    #pragma unroll
    for (int i = 0; i < 4; ++i) {
        #pragma unroll
        for (int r = 0; r < 4; ++r) {
            int row = m0 + wm + i * 16 + (lane >> 4) * 4 + r;
            #pragma unroll
            for (int j = 0; j < 4; ++j) {
                float v  = acc[i][j][r];
                float vn = __shfl_xor(v, 1);
                int cN = wn + j * 16 + r15;
                if (row < M && !(r15 & 1)) {
                    if (cN < 128) {
                        *reinterpret_cast<unsigned*>(&PS[(size_t)row * 128 + cN]) = packbf(v, vn);
                    } else {
                        unsigned p8 = __builtin_amdgcn_cvt_pk_fp8_f32(v, vn, 0u, false);
                        *reinterpret_cast<unsigned short*>(&PN8[(size_t)row * 128 + (cN - 128)]) =
                            (unsigned short)p8;
                    }
                }
            }
        }
    }
}

// fp8x8 (one uint2) -> 8 f32 accumulate via HW v_cvt_pk_f32_fp8
__device__ __forceinline__ void acc_fp8x8(uint2 u,
                                          float& a0, float& a1, float& a2, float& a3,
                                          float& a4, float& a5, float& a6, float& a7) {
    auto f01 = __builtin_amdgcn_cvt_pk_f32_fp8(u.x, false);
    auto f23 = __builtin_amdgcn_cvt_pk_f32_fp8(u.x, true);
    auto f45 = __builtin_amdgcn_cvt_pk_f32_fp8(u.y, false);
    auto f67 = __builtin_amdgcn_cvt_pk_f32_fp8(u.y, true);
    a0 += f01[0]; a1 += f01[1]; a2 += f23[0]; a3 += f23[1];
    a4 += f45[0]; a5 += f45[1]; a6 += f67[0]; a7 += f67[1];
}

// ---------------- gather-aggregate + combine + relu: one wave per node ----------------
// PN stored fp8 e4m3: 128B/row -> random working set 12.8MB, half the L2-miss bytes.
__global__ __launch_bounds__(256) void gather_combine(const unsigned short* __restrict__ PS,
                                                      const unsigned char* __restrict__ PN8,
                                                      const int* __restrict__ row_ptr,
                                                      const int* __restrict__ csr_cols,
                                                      const float* __restrict__ invdeg,
                                                      unsigned short* __restrict__ H, int N) {
    int node = (blockIdx.x * blockDim.x + threadIdx.x) >> 6;
    if (node >= N) return;
    int lane = threadIdx.x & 63;
    int grp  = lane >> 4;
    int l16  = lane & 15;
    int beg = row_ptr[node], end = row_ptr[node + 1];

    float id = 0.f;
    uint4 us = {0u, 0u, 0u, 0u};
    if (grp == 0) {
        id = invdeg[node];
        us = *reinterpret_cast<const uint4*>(&PS[(size_t)node * 128 + l16 * 8]);
    }

    float a0=0,a1=0,a2=0,a3=0,a4=0,a5=0,a6=0,a7=0;
    int p0 = beg + grp;
    for (; p0 + 12 < end; p0 += 16) {
        int cA = csr_cols[p0];
        int cB = csr_cols[p0 + 4];
        int cC = csr_cols[p0 + 8];
        int cD = csr_cols[p0 + 12];
        uint2 uA = *reinterpret_cast<const uint2*>(&PN8[(size_t)cA * 128 + l16 * 8]);
        uint2 uB = *reinterpret_cast<const uint2*>(&PN8[(size_t)cB * 128 + l16 * 8]);
        uint2 uC = *reinterpret_cast<const uint2*>(&PN8[(size_t)cC * 128 + l16 * 8]);
        uint2 uD = *reinterpret_cast<const uint2*>(&PN8[(size_t)cD * 128 + l16 * 8]);
        acc_fp8x8(uA, a0, a1, a2, a3, a4, a5, a6, a7);
        acc_fp8x8(uB, a0, a1, a2, a3, a4, a5, a6, a7);
        acc_fp8x8(uC, a0, a1, a2, a3, a4, a5, a6, a7);
        acc_fp8x8(uD, a0, a1, a2, a3, a4, a5, a6, a7);
    }
    for (; p0 < end; p0 += 4) {
        int c = csr_cols[p0];
        uint2 u = *reinterpret_cast<const uint2*>(&PN8[(size_t)c * 128 + l16 * 8]);
        acc_fp8x8(u, a0, a1, a2, a3, a4, a5, a6, a7);
    }
    a0 += __shfl_xor(a0, 16); a1 += __shfl_xor(a1, 16);
    a2 += __shfl_xor(a2, 16); a3 += __shfl_xor(a3, 16);
    a4 += __shfl_xor(a4, 16); a5 += __shfl_xor(a5, 16);
    a6 += __shfl_xor(a6, 16); a7 += __shfl_xor(a7, 16);
    a0 += __shfl_xor(a0, 32); a1 += __shfl_xor(a1, 32);
    a2 += __shfl_xor(a2, 32); a3 += __shfl_xor(a3, 32);
    a4 += __shfl_xor(a4, 32); a5 += __shfl_xor(a5, 32);
    a6 += __shfl_xor(a6, 32); a7 += __shfl_xor(a7, 32);

    if (grp == 0) {
        float h0 = fmaxf(fmaf(a0, id, bflo(us.x)), 0.f);
        float h1 = fmaxf(fmaf(a1, id, bfhi(us.x)), 0.f);
        float h2 = fmaxf(fmaf(a2, id, bflo(us.y)), 0.f);
        float h3 = fmaxf(fmaf(a3, id, bfhi(us.y)), 0.f);
        float h4 = fmaxf(fmaf(a4, id, bflo(us.z)), 0.f);
        float h5 = fmaxf(fmaf(a5, id, bfhi(us.z)), 0.f);
        float h6 = fmaxf(fmaf(a6, id, bflo(us.w)), 0.f);
        float h7 = fmaxf(fmaf(a7, id, bfhi(us.w)), 0.f);
        uint4 o;
        o.x = packbf(h0, h1); o.y = packbf(h2, h3);
        o.z = packbf(h4, h5); o.w = packbf(h6, h7);
        *reinterpret_cast<uint4*>(&H[(size_t)node * 128 + l16 * 8]) = o;
    }
}

// ---------------- MFMA head: logits = H @ Wb^T (+bias), fused log_softmax ----------------
__global__ __launch_bounds__(256) void mlp_head_mfma(const unsigned short* __restrict__ H,
                                                     const unsigned short* __restrict__ Wb,
                                                     const float* __restrict__ bm,
                                                     float* __restrict__ out, int N) {
    __shared__ unsigned short sW[48 * 128];   // 12 KB
    int t = threadIdx.x;
    for (int i = t; i < 48 * 128 / 2; i += 256)
        ((unsigned*)sW)[i] = ((const unsigned*)Wb)[i];
    __syncthreads();

    const int wave = t >> 6, lane = t & 63;
    const int m0 = blockIdx.x * 64 + wave * 16;
    if (m0 >= N) return;
    const int r15 = lane & 15;
    const int k8  = (lane >> 4) * 8;
    const int arow = min(m0 + r15, N - 1);

    float4v acc[3] = {{0.f,0.f,0.f,0.f},{0.f,0.f,0.f,0.f},{0.f,0.f,0.f,0.f}};
    #pragma unroll
    for (int k0 = 0; k0 < 128; k0 += 32) {
        short8 a = *reinterpret_cast<const short8*>(&H[(size_t)arow * 128 + k0 + k8]);
        #pragma unroll
        for (int f = 0; f < 3; ++f) {
            short8 b = *reinterpret_cast<const short8*>(&sW[(f * 16 + r15) * 128 + k0 + k8]);
            acc[f] = __builtin_amdgcn_mfma_f32_16x16x32_bf16(a, b, acc[f], 0, 0, 0);
        }
    }

    float bias[3]; bool cv[3];
    #pragma unroll
    for (int f = 0; f < 3; ++f) {
        int c = f * 16 + r15;
        cv[f] = (c < NCLASS);
        bias[f] = cv[f] ? bm[c] : 0.f;
    }
    #pragma unroll
    for (int r = 0; r < 4; ++r) {
        int node = m0 + (lane >> 4) * 4 + r;
        float lg[3];
        float m = -1e30f;
        #pragma unroll
        for (int f = 0; f < 3; ++f) {
            lg[f] = cv[f] ? (acc[f][r] + bias[f]) : -1e30f;
            m = fmaxf(m, lg[f]);
        }
        m = fmaxf(m, __shfl_xor(m, 1));
        m = fmaxf(m, __shfl_xor(m, 2));
        m = fmaxf(m, __shfl_xor(m, 4));
        m = fmaxf(m, __shfl_xor(m, 8));
        float s = 0.f;
        #pragma unroll
        for (int f = 0; f < 3; ++f) s += cv[f] ? __expf(lg[f] - m) : 0.f;
        s += __shfl_xor(s, 1);
        s += __shfl_xor(s, 2);
        s += __shfl_xor(s, 4);
        s += __shfl_xor(s, 8);
        float ls = __logf(s);
        if (node < N) {
            #pragma unroll
            for (int f = 0; f < 3; ++f)
                if (cv[f]) out[(size_t)node * NCLASS + f * 16 + r15] = lg[f] - m - ls;
        }
    }
}

extern "C" void kernel_launch(void* const* d_in, const int* in_sizes, int n_in,
                              void* d_out, int out_size, void* d_ws, size_t ws_size,
                              hipStream_t stream) {
    const float* x    = (const float*)d_in[0];
    const float* W1   = (const float*)d_in[1];
    const float* W2   = (const float*)d_in[2];
    const float* mlpW = (const float*)d_in[3];
    const float* mlpb = (const float*)d_in[4];
    const int*   rows = (const int*)d_in[5];
    const int*   cols = (const int*)d_in[6];

    const int N = in_sizes[0] / NFEAT;   // 100000
    const int E = in_sizes[5];           // 3200000

    char* ws = (char*)d_ws;
    size_t off = 0;
    auto alloc = [&](size_t bytes) -> void* {
        void* p = ws + off;
        off = (off + bytes + 255) & ~(size_t)255;
        return p;
    };
    unsigned short* PS  = (unsigned short*)alloc((size_t)N * 128 * 2);  // self-projection (bf16)
    unsigned char*  PN8 = (unsigned char*) alloc((size_t)N * 128);      // neigh-projection (fp8 e4m3)
    unsigned short* H   = (unsigned short*)alloc((size_t)N * 128 * 2);  // hidden (bf16)
    float* INV    = (float*)alloc((size_t)N * 4);
    int*   ROWP   = (int*)  alloc((size_t)(N + 1) * 4);
    int*   CSRC   = (int*)  alloc((size_t)E * 4);
    unsigned* BINNED = (unsigned*)alloc((size_t)E * 4);
    int*   GHIST  = (int*)  alloc((size_t)256 * 4);
    int*   GBASE  = (int*)  alloc((size_t)257 * 4);
    int*   GCUR   = (int*)  alloc((size_t)256 * 4);
    unsigned short* Wp1 = (unsigned short*)alloc((size_t)256 * 256 * 2);
    unsigned short* Wp2 = (unsigned short*)alloc((size_t)128 * 256 * 2);
    unsigned short* Wb  = (unsigned short*)alloc((size_t)48 * 128 * 2);

    const int nbuck = (N + 511) >> 9;              // 196
    const int nblk  = (E + TILE_E - 1) / TILE_E;   // 782

    // Per-block histograms from K1, consumed by K3. Aliased into CSRC's space:
    // CSRC is only written by fill_win (K4), which runs after bin_scatter (K3)
    // has finished reading BH. nblk*256*4 = 800KB <= E*4 = 12.8MB.
    int* BH = (int*)CSRC;

    // ---- CSR build via LDS-histogram binning (also produces row_ptr + inv_deg) ----
    hipMemsetAsync(GHIST, 0, 256 * 4, stream);
    bin_hist<<<nblk, 256, 0, stream>>>(rows, GHIST, BH, E, nbuck);
    scan_buckets<<<1, 256, 0, stream>>>(GHIST, GBASE, GCUR, ROWP, nbuck, N, E);
    bin_scatter<<<nblk, 256, 0, stream>>>(rows, cols, BH, GCUR, BINNED, E, nbuck);
    fill_win<<<nbuck, 256, 0, stream>>>(BINNED, GBASE, ROWP, INV, CSRC, N);

    // ---- weight prep ----
    repack_all<<<560, 256, 0, stream>>>(W1, W2, mlpW, Wp1, Wp2, Wb);

    const int mblocks = (N + 127) / 128;   // 782
    const int gblocks = (int)(((long long)N * 64 + 255) / 256);

    // ---- layer 1 (reads fp32 x ONCE; PN written fp8) ----
    gemm1_mfma<<<mblocks, 512, 0, stream>>>(x, Wp1, PS, PN8, N);
    gather_combine<<<gblocks, 256, 0, stream>>>(PS, PN8, ROWP, CSRC, INV, H, N);

    // ---- layer 2 ----
    gemm2_mfma<<<mblocks, 512, 0, stream>>>(H, Wp2, PS, PN8, N);
    gather_combine<<<gblocks, 256, 0, stream>>>(PS, PN8, ROWP, CSRC, INV, H, N);

    // ---- head ----
    mlp_head_mfma<<<(N + 63) / 64, 256, 0, stream>>>(H, Wb, mlpb, (float*)d_out, N);
}

// Round 5
// 447.686 us; speedup vs baseline: 1.2654x; 1.0623x over previous
//
#include <hip/hip_runtime.h>
#include <hip/hip_bf16.h>

#define NFEAT 256
#define NHID  128
#define NCLASS 40

typedef __attribute__((ext_vector_type(8))) short short8;
typedef __attribute__((ext_vector_type(4))) float float4v;

__device__ __forceinline__ unsigned short f2bf(float f) {
    union { float f; unsigned u; } v; v.f = f;
    unsigned r = v.u + 0x7fff + ((v.u >> 16) & 1);   // RNE
    return (unsigned short)(r >> 16);
}
__device__ __forceinline__ float bflo(unsigned u) { return __uint_as_float(u << 16); }
__device__ __forceinline__ float bfhi(unsigned u) { return __uint_as_float(u & 0xffff0000u); }
// HW packed f32x2 -> bf16x2 (RNE), single VALU op; low half = a, high = b
__device__ __forceinline__ unsigned cvtpk_bf16(float a, float b) {
    unsigned r;
    asm("v_cvt_pk_bf16_f32 %0, %1, %2" : "=v"(r) : "v"(a), "v"(b));
    return r;
}

// async global->LDS, 16B per lane; LDS dest = wave-uniform base + lane*16
__device__ __forceinline__ void ld_g2l16(const unsigned short* gp, unsigned short* lp) {
    __builtin_amdgcn_global_load_lds((const __attribute__((address_space(1))) unsigned short*)gp,
                                     (__attribute__((address_space(3))) unsigned short*)lp,
                                     16, 0, 0);
}

#define TILE_E 4096   // edges per binning block
#define WCAP   20480  // padded slots per 512-row window (mean 16384, sigma~128 -> +32 sigma)

// ---- K1: tile histogram (regs-stashed) + per-bucket chunk reserve + scatter ----
// packed entry: (row & 511) << 17 | col   (col < 2^17)
// Window w's edges land in binned[w*WCAP .. w*WCAP + gcur[w])  (padded, unordered)
__global__ __launch_bounds__(256) void bin_scatter(const int* __restrict__ rows,
                                                   const int* __restrict__ cols,
                                                   int* __restrict__ gcur,
                                                   unsigned* __restrict__ binned, int E, int nbuck) {
    __shared__ int hh[256];
    __shared__ int lbase[256];
    __shared__ int lcur[256];
    int t = threadIdx.x;
    hh[t] = 0;
    __syncthreads();
    int e0 = blockIdx.x * TILE_E;
    int4 rv[4];
    #pragma unroll
    for (int it = 0; it < TILE_E / 1024; ++it) {
        int base = e0 + (it * 256 + t) * 4;
        if (base + 3 < E) {
            rv[it] = *reinterpret_cast<const int4*>(&rows[base]);
            atomicAdd(&hh[rv[it].x >> 9], 1);
            atomicAdd(&hh[rv[it].y >> 9], 1);
            atomicAdd(&hh[rv[it].z >> 9], 1);
            atomicAdd(&hh[rv[it].w >> 9], 1);
        } else {
            for (int k = 0; k < 4; ++k)
                if (base + k < E) atomicAdd(&hh[rows[base + k] >> 9], 1);
        }
    }
    __syncthreads();
    if (t < nbuck) {
        int h = hh[t];
        lbase[t] = t * WCAP + (h ? atomicAdd(&gcur[t], h) : 0);
        lcur[t] = 0;
    }
    __syncthreads();
    #pragma unroll
    for (int it = 0; it < TILE_E / 1024; ++it) {
        int base = e0 + (it * 256 + t) * 4;
        if (base + 3 < E) {
            int4 r = rv[it];
            int4 c = *reinterpret_cast<const int4*>(&cols[base]);
            int b0 = r.x >> 9, b1 = r.y >> 9, b2 = r.z >> 9, b3 = r.w >> 9;
            int d0 = lbase[b0] + atomicAdd(&lcur[b0], 1);
            int d1 = lbase[b1] + atomicAdd(&lcur[b1], 1);
            int d2 = lbase[b2] + atomicAdd(&lcur[b2], 1);
            int d3 = lbase[b3] + atomicAdd(&lcur[b3], 1);
            binned[d0] = ((unsigned)(r.x & 511) << 17) | (unsigned)c.x;
            binned[d1] = ((unsigned)(r.y & 511) << 17) | (unsigned)c.y;
            binned[d2] = ((unsigned)(r.z & 511) << 17) | (unsigned)c.z;
            binned[d3] = ((unsigned)(r.w & 511) << 17) | (unsigned)c.w;
        } else {
            for (int k = 0; k < 4; ++k)
                if (base + k < E) {
                    int r = rows[base + k];
                    int b = r >> 9;
                    int dst = lbase[b] + atomicAdd(&lcur[b], 1);
                    binned[dst] = ((unsigned)(r & 511) << 17) | (unsigned)cols[base + k];
                }
        }
    }
}

// ---- K2: one block per window: degrees+scan -> RPD{beg,deg,invdeg}, ordered CSR cols ----
__global__ __launch_bounds__(256) void fill_win(const unsigned* __restrict__ binned,
                                                const int* __restrict__ gcur,
                                                int4* __restrict__ rpd,
                                                int* __restrict__ csr_cols, int N) {
    __shared__ int h[512];
    __shared__ int ps[256];
    __shared__ int lcur[512];
    int t = threadIdx.x;
    int w = blockIdx.x;
    int r0 = w << 9;
    h[t] = 0; h[t + 256] = 0;
    __syncthreads();
    int beg = w * WCAP, end = beg + gcur[w];
    for (int e = beg + t; e < end; e += 256)
        atomicAdd(&h[binned[e] >> 17], 1);
    __syncthreads();
    int pair = h[2 * t] + h[2 * t + 1];
    ps[t] = pair;
    __syncthreads();
    for (int off = 1; off < 256; off <<= 1) {
        int tmp = (t >= off) ? ps[t - off] : 0;
        __syncthreads();
        ps[t] += tmp;
        __syncthreads();
    }
    int base0 = beg + ps[t] - pair;
    int base1 = base0 + h[2 * t];
    int r_a = r0 + 2 * t, r_b = r0 + 2 * t + 1;
    if (r_a < N) {
        int4 m; m.x = base0; m.y = h[2 * t];
        m.z = __float_as_int(1.0f / ((float)h[2 * t] + 1.0f)); m.w = 0;
        rpd[r_a] = m;
    }
    if (r_b < N) {
        int4 m; m.x = base1; m.y = h[2 * t + 1];
        m.z = __float_as_int(1.0f / ((float)h[2 * t + 1] + 1.0f)); m.w = 0;
        rpd[r_b] = m;
    }
    lcur[2 * t] = base0;
    lcur[2 * t + 1] = base1;
    __syncthreads();
    for (int e = beg + t; e < end; e += 256) {
        unsigned v = binned[e];
        int idx = atomicAdd(&lcur[v >> 17], 1);
        csr_cols[idx] = (int)(v & 0x1FFFFu);
    }
}

// ---------------- fused weight repack (W1, W2 -> K-panels; Wm -> padded bf16) ----------------
// Wp layout: [k0/32][o(256)][k(32)]
__global__ __launch_bounds__(256) void repack_all(const float* __restrict__ W1,
                                                  const float* __restrict__ W2,
                                                  const float* __restrict__ Wm,
                                                  unsigned short* __restrict__ Wp1,
                                                  unsigned short* __restrict__ Wp2,
                                                  unsigned short* __restrict__ Wb) {
    int b = blockIdx.x, t = threadIdx.x;
    if (b < 256) {                       // W1: o=b (0..255), k=t (0..255)
        float v = (b < 128) ? W1[b * 512 + t] : W1[(b - 128) * 512 + 256 + t];
        Wp1[(size_t)(t >> 5) * 256 * 32 + b * 32 + (t & 31)] = f2bf(v);
    } else if (b < 512) {                // W2: o=b-256 (0..255), k=t (0..127)
        int o = b - 256;
        if (t < 128) {
            float v = (o < 128) ? W2[o * 256 + t] : W2[(o - 128) * 256 + 128 + t];
            Wp2[(size_t)(t >> 5) * 256 * 32 + o * 32 + (t & 31)] = f2bf(v);
        }
    } else {                             // Wm: o=b-512 (0..47), k=t (0..127)
        int o = b - 512;
        if (t < 128) Wb[o * 128 + t] = (o < NCLASS) ? f2bf(Wm[o * 128 + t]) : 0;
    }
}

// ---------------- layer-1 GEMM: [PS|PN8] = bf16(x[M x 256]) @ Wp1 ----------------
// BM=128, BN=256 (one pass over x), 8 waves; A cvt via v_cvt_pk_bf16_f32, B via global_load_lds.
// PS (self half) bf16; PN (neigh half) fp8 e4m3 via HW cvt (halves gather bytes).
__global__ __launch_bounds__(512) void gemm1_mfma(const float* __restrict__ X,
                                                  const unsigned short* __restrict__ Wp,
                                                  unsigned short* __restrict__ PS,
                                                  unsigned char* __restrict__ PN8,
                                                  int M) {
    __shared__ unsigned short sA[128 * 32];
    __shared__ unsigned short sB[256 * 32];
    const int t    = threadIdx.x;
    const int lane = t & 63;
    const int wave = t >> 6;              // 0..7
    const int m0 = blockIdx.x * 128;
    const int wm = (wave >> 2) * 64;      // 0 or 64
    const int wn = (wave & 3) * 64;       // 0,64,128,192

    const int r15 = lane & 15;
    const int k8  = (lane >> 4) * 8;
    const int arow = t >> 2;              // 0..127
    const int ac8  = (t & 3) * 8;
    const int brow = lane >> 2;           // 0..15
    const int bc8  = (lane & 3) * 8;

    float4v acc[4][4] = {{{0.f,0.f,0.f,0.f}}};
    const int gm = min(m0 + arow, M - 1);        // clamp: x is an input alloc
    const float* gA = X + (size_t)gm * 256 + ac8;

    for (int k0 = 0; k0 < 256; k0 += 32) {
        const unsigned short* pan = Wp + (size_t)(k0 >> 5) * 256 * 32;
        float4 v0 = *reinterpret_cast<const float4*>(gA + k0);
        float4 v1 = *reinterpret_cast<const float4*>(gA + k0 + 4);
        uint4 q;
        q.x = cvtpk_bf16(v0.x, v0.y);
        q.y = cvtpk_bf16(v0.z, v0.w);
        q.z = cvtpk_bf16(v1.x, v1.y);
        q.w = cvtpk_bf16(v1.z, v1.w);
        *reinterpret_cast<uint4*>(&sA[arow * 32 + ac8]) = q;
        #pragma unroll
        for (int it = 0; it < 2; ++it) {
            int slab = it * 128 + wave * 16;
            ld_g2l16(pan + (size_t)(slab + brow) * 32 + bc8, &sB[slab * 32]);
        }
        __syncthreads();

        short8 aF[4], bF[4];
        #pragma unroll
        for (int i = 0; i < 4; ++i)
            aF[i] = *reinterpret_cast<const short8*>(&sA[(wm + i * 16 + r15) * 32 + k8]);
        #pragma unroll
        for (int j = 0; j < 4; ++j)
            bF[j] = *reinterpret_cast<const short8*>(&sB[(wn + j * 16 + r15) * 32 + k8]);
        #pragma unroll
        for (int i = 0; i < 4; ++i)
            #pragma unroll
            for (int j = 0; j < 4; ++j)
                acc[i][j] = __builtin_amdgcn_mfma_f32_16x16x32_bf16(aF[i], bF[j], acc[i][j], 0, 0, 0);
        __syncthreads();
    }

    #pragma unroll
    for (int i = 0; i < 4; ++i) {
        #pragma unroll
        for (int r = 0; r < 4; ++r) {
            int row = m0 + wm + i * 16 + (lane >> 4) * 4 + r;
            #pragma unroll
            for (int j = 0; j < 4; ++j) {
                float v  = acc[i][j][r];
                float vn = __shfl_xor(v, 1);
                int cN = wn + j * 16 + r15;
                if (row < M && !(r15 & 1)) {
                    if (cN < 128) {
                        *reinterpret_cast<unsigned*>(&PS[(size_t)row * 128 + cN]) = cvtpk_bf16(v, vn);
                    } else {
                        unsigned p8 = __builtin_amdgcn_cvt_pk_fp8_f32(v, vn, 0u, false);
                        *reinterpret_cast<unsigned short*>(&PN8[(size_t)row * 128 + (cN - 128)]) =
                            (unsigned short)p8;
                    }
                }
            }
        }
    }
}

// ---------------- layer-2 GEMM: [PS|PN8] = H[M x 128] @ Wp2, async A+B staging ----------------
// BM=128, BN=256 (one pass over H). A-tail of last M-block overreads into adjacent ws — safe.
__global__ __launch_bounds__(512) void gemm2_mfma(const unsigned short* __restrict__ H,
                                                  const unsigned short* __restrict__ Wp,
                                                  unsigned short* __restrict__ PS,
                                                  unsigned char* __restrict__ PN8,
                                                  int M) {
    __shared__ unsigned short sA[128 * 32];
    __shared__ unsigned short sB[256 * 32];
    const int t    = threadIdx.x;
    const int lane = t & 63;
    const int wave = t >> 6;
    const int m0 = blockIdx.x * 128;
    const int wm = (wave >> 2) * 64;
    const int wn = (wave & 3) * 64;

    const int r15 = lane & 15;
    const int k8  = (lane >> 4) * 8;
    const int brow = lane >> 2;
    const int bc8  = (lane & 3) * 8;

    float4v acc[4][4] = {{{0.f,0.f,0.f,0.f}}};

    for (int k0 = 0; k0 < 128; k0 += 32) {
        const unsigned short* pan = Wp + (size_t)(k0 >> 5) * 256 * 32;
        int slabA = wave * 16;
        ld_g2l16(H + (size_t)(m0 + slabA + brow) * 128 + k0 + bc8, &sA[slabA * 32]);
        #pragma unroll
        for (int it = 0; it < 2; ++it) {
            int slab = it * 128 + wave * 16;
            ld_g2l16(pan + (size_t)(slab + brow) * 32 + bc8, &sB[slab * 32]);
        }
        __syncthreads();

        short8 aF[4], bF[4];
        #pragma unroll
        for (int i = 0; i < 4; ++i)
            aF[i] = *reinterpret_cast<const short8*>(&sA[(wm + i * 16 + r15) * 32 + k8]);
        #pragma unroll
        for (int j = 0; j < 4; ++j)
            bF[j] = *reinterpret_cast<const short8*>(&sB[(wn + j * 16 + r15) * 32 + k8]);
        #pragma unroll
        for (int i = 0; i < 4; ++i)
            #pragma unroll
            for (int j = 0; j < 4; ++j)
                acc[i][j] = __builtin_amdgcn_mfma_f32_16x16x32_bf16(aF[i], bF[j], acc[i][j], 0, 0, 0);
        __syncthreads();
    }

    #pragma unroll
    for (int i = 0; i < 4; ++i) {
        #pragma unroll
        for (int r = 0; r < 4; ++r) {
            int row = m0 + wm + i * 16 + (lane >> 4) * 4 + r;
            #pragma unroll
            for (int j = 0; j < 4; ++j) {
                float v  = acc[i][j][r];
                float vn = __shfl_xor(v, 1);
                int cN = wn + j * 16 + r15;
                if (row < M && !(r15 & 1)) {
                    if (cN < 128) {
                        *reinterpret_cast<unsigned*>(&PS[(size_t)row * 128 + cN]) = cvtpk_bf16(v, vn);
                    } else {
                        unsigned p8 = __builtin_amdgcn_cvt_pk_fp8_f32(v, vn, 0u, false);
                        *reinterpret_cast<unsigned short*>(&PN8[(size_t)row * 128 + (cN - 128)]) =
                            (unsigned short)p8;
                    }
                }
            }
        }
    }
}

// fp8x8 (one uint2) -> 8 f32 accumulate via HW v_cvt_pk_f32_fp8
__device__ __forceinline__ void acc_fp8x8(uint2 u,
                                          float& a0, float& a1, float& a2, float& a3,
                                          float& a4, float& a5, float& a6, float& a7) {
    auto f01 = __builtin_amdgcn_cvt_pk_f32_fp8(u.x, false);
    auto f23 = __builtin_amdgcn_cvt_pk_f32_fp8(u.x, true);
    auto f45 = __builtin_amdgcn_cvt_pk_f32_fp8(u.y, false);
    auto f67 = __builtin_amdgcn_cvt_pk_f32_fp8(u.y, true);
    a0 += f01[0]; a1 += f01[1]; a2 += f23[0]; a3 += f23[1];
    a4 += f45[0]; a5 += f45[1]; a6 += f67[0]; a7 += f67[1];
}

// ---------------- gather-aggregate + combine + relu: one wave per node ----------------
// PN fp8: 128B/row random working set 12.8MB. Node metadata (beg,deg,invdeg) in one int4.
__global__ __launch_bounds__(256) void gather_combine(const unsigned short* __restrict__ PS,
                                                      const unsigned char* __restrict__ PN8,
                                                      const int4* __restrict__ rpd,
                                                      const int* __restrict__ csr_cols,
                                                      unsigned short* __restrict__ H, int N) {
    int node = (blockIdx.x * blockDim.x + threadIdx.x) >> 6;
    if (node >= N) return;
    int lane = threadIdx.x & 63;
    int grp  = lane >> 4;
    int l16  = lane & 15;
    int4 md = rpd[node];
    int beg = md.x, end = md.x + md.y;
    float id = __int_as_float(md.z);

    uint4 us = {0u, 0u, 0u, 0u};
    if (grp == 0)
        us = *reinterpret_cast<const uint4*>(&PS[(size_t)node * 128 + l16 * 8]);

    float a0=0,a1=0,a2=0,a3=0,a4=0,a5=0,a6=0,a7=0;
    int p0 = beg + grp;
    for (; p0 + 12 < end; p0 += 16) {
        int cA = csr_cols[p0];
        int cB = csr_cols[p0 + 4];
        int cC = csr_cols[p0 + 8];
        int cD = csr_cols[p0 + 12];
        uint2 uA = *reinterpret_cast<const uint2*>(&PN8[(size_t)cA * 128 + l16 * 8]);
        uint2 uB = *reinterpret_cast<const uint2*>(&PN8[(size_t)cB * 128 + l16 * 8]);
        uint2 uC = *reinterpret_cast<const uint2*>(&PN8[(size_t)cC * 128 + l16 * 8]);
        uint2 uD = *reinterpret_cast<const uint2*>(&PN8[(size_t)cD * 128 + l16 * 8]);
        acc_fp8x8(uA, a0, a1, a2, a3, a4, a5, a6, a7);
        acc_fp8x8(uB, a0, a1, a2, a3, a4, a5, a6, a7);
        acc_fp8x8(uC, a0, a1, a2, a3, a4, a5, a6, a7);
        acc_fp8x8(uD, a0, a1, a2, a3, a4, a5, a6, a7);
    }
    for (; p0 < end; p0 += 4) {
        int c = csr_cols[p0];
        uint2 u = *reinterpret_cast<const uint2*>(&PN8[(size_t)c * 128 + l16 * 8]);
        acc_fp8x8(u, a0, a1, a2, a3, a4, a5, a6, a7);
    }
    a0 += __shfl_xor(a0, 16); a1 += __shfl_xor(a1, 16);
    a2 += __shfl_xor(a2, 16); a3 += __shfl_xor(a3, 16);
    a4 += __shfl_xor(a4, 16); a5 += __shfl_xor(a5, 16);
    a6 += __shfl_xor(a6, 16); a7 += __shfl_xor(a7, 16);
    a0 += __shfl_xor(a0, 32); a1 += __shfl_xor(a1, 32);
    a2 += __shfl_xor(a2, 32); a3 += __shfl_xor(a3, 32);
    a4 += __shfl_xor(a4, 32); a5 += __shfl_xor(a5, 32);
    a6 += __shfl_xor(a6, 32); a7 += __shfl_xor(a7, 32);

    if (grp == 0) {
        float h0 = fmaxf(fmaf(a0, id, bflo(us.x)), 0.f);
        float h1 = fmaxf(fmaf(a1, id, bfhi(us.x)), 0.f);
        float h2 = fmaxf(fmaf(a2, id, bflo(us.y)), 0.f);
        float h3 = fmaxf(fmaf(a3, id, bfhi(us.y)), 0.f);
        float h4 = fmaxf(fmaf(a4, id, bflo(us.z)), 0.f);
        float h5 = fmaxf(fmaf(a5, id, bfhi(us.z)), 0.f);
        float h6 = fmaxf(fmaf(a6, id, bflo(us.w)), 0.f);
        float h7 = fmaxf(fmaf(a7, id, bfhi(us.w)), 0.f);
        uint4 o;
        o.x = cvtpk_bf16(h0, h1); o.y = cvtpk_bf16(h2, h3);
        o.z = cvtpk_bf16(h4, h5); o.w = cvtpk_bf16(h6, h7);
        *reinterpret_cast<uint4*>(&H[(size_t)node * 128 + l16 * 8]) = o;
    }
}

// ---------------- MFMA head: logits = H @ Wb^T (+bias), fused log_softmax ----------------
__global__ __launch_bounds__(256) void mlp_head_mfma(const unsigned short* __restrict__ H,
                                                     const unsigned short* __restrict__ Wb,
                                                     const float* __restrict__ bm,
                                                     float* __restrict__ out, int N) {
    __shared__ unsigned short sW[48 * 128];   // 12 KB
    int t = threadIdx.x;
    for (int i = t; i < 48 * 128 / 2; i += 256)
        ((unsigned*)sW)[i] = ((const unsigned*)Wb)[i];
    __syncthreads();

    const int wave = t >> 6, lane = t & 63;
    const int m0 = blockIdx.x * 64 + wave * 16;
    if (m0 >= N) return;
    const int r15 = lane & 15;
    const int k8  = (lane >> 4) * 8;
    const int arow = min(m0 + r15, N - 1);

    float4v acc[3] = {{0.f,0.f,0.f,0.f},{0.f,0.f,0.f,0.f},{0.f,0.f,0.f,0.f}};
    #pragma unroll
    for (int k0 = 0; k0 < 128; k0 += 32) {
        short8 a = *reinterpret_cast<const short8*>(&H[(size_t)arow * 128 + k0 + k8]);
        #pragma unroll
        for (int f = 0; f < 3; ++f) {
            short8 b = *reinterpret_cast<const short8*>(&sW[(f * 16 + r15) * 128 + k0 + k8]);
            acc[f] = __builtin_amdgcn_mfma_f32_16x16x32_bf16(a, b, acc[f], 0, 0, 0);
        }
    }

    float bias[3]; bool cv[3];
    #pragma unroll
    for (int f = 0; f < 3; ++f) {
        int c = f * 16 + r15;
        cv[f] = (c < NCLASS);
        bias[f] = cv[f] ? bm[c] : 0.f;
    }
    #pragma unroll
    for (int r = 0; r < 4; ++r) {
        int node = m0 + (lane >> 4) * 4 + r;
        float lg[3];
        float m = -1e30f;
        #pragma unroll
        for (int f = 0; f < 3; ++f) {
            lg[f] = cv[f] ? (acc[f][r] + bias[f]) : -1e30f;
            m = fmaxf(m, lg[f]);
        }
        m = fmaxf(m, __shfl_xor(m, 1));
        m = fmaxf(m, __shfl_xor(m, 2));
        m = fmaxf(m, __shfl_xor(m, 4));
        m = fmaxf(m, __shfl_xor(m, 8));
        float s = 0.f;
        #pragma unroll
        for (int f = 0; f < 3; ++f) s += cv[f] ? __expf(lg[f] - m) : 0.f;
        s += __shfl_xor(s, 1);
        s += __shfl_xor(s, 2);
        s += __shfl_xor(s, 4);
        s += __shfl_xor(s, 8);
        float ls = __logf(s);
        if (node < N) {
            #pragma unroll
            for (int f = 0; f < 3; ++f)
                if (cv[f]) out[(size_t)node * NCLASS + f * 16 + r15] = lg[f] - m - ls;
        }
    }
}

extern "C" void kernel_launch(void* const* d_in, const int* in_sizes, int n_in,
                              void* d_out, int out_size, void* d_ws, size_t ws_size,
                              hipStream_t stream) {
    const float* x    = (const float*)d_in[0];
    const float* W1   = (const float*)d_in[1];
    const float* W2   = (const float*)d_in[2];
    const float* mlpW = (const float*)d_in[3];
    const float* mlpb = (const float*)d_in[4];
    const int*   rows = (const int*)d_in[5];
    const int*   cols = (const int*)d_in[6];

    const int N = in_sizes[0] / NFEAT;   // 100000
    const int E = in_sizes[5];           // 3200000

    char* ws = (char*)d_ws;
    size_t off = 0;
    auto alloc = [&](size_t bytes) -> void* {
        void* p = ws + off;
        off = (off + bytes + 255) & ~(size_t)255;
        return p;
    };
    const int nbuck = (N + 511) >> 9;              // 196
    const int nblk  = (E + TILE_E - 1) / TILE_E;   // 782

    unsigned short* PS  = (unsigned short*)alloc((size_t)N * 128 * 2);  // self-projection (bf16)
    unsigned char*  PN8 = (unsigned char*) alloc((size_t)N * 128);      // neigh-projection (fp8 e4m3)
    unsigned short* H   = (unsigned short*)alloc((size_t)N * 128 * 2);  // hidden (bf16)
    int4*  RPD    = (int4*) alloc((size_t)N * 16);                      // {beg, deg, invdeg, 0}
    int*   CSRC   = (int*)  alloc((size_t)nbuck * WCAP * 4);            // padded CSR cols
    unsigned* BINNED = (unsigned*)alloc((size_t)nbuck * WCAP * 4);      // padded window bins
    int*   GCUR   = (int*)  alloc((size_t)256 * 4);
    unsigned short* Wp1 = (unsigned short*)alloc((size_t)256 * 256 * 2);
    unsigned short* Wp2 = (unsigned short*)alloc((size_t)128 * 256 * 2);
    unsigned short* Wb  = (unsigned short*)alloc((size_t)48 * 128 * 2);

    // ---- CSR build: padded windows (no global hist/scan passes) ----
    hipMemsetAsync(GCUR, 0, 256 * 4, stream);
    bin_scatter<<<nblk, 256, 0, stream>>>(rows, cols, GCUR, BINNED, E, nbuck);
    fill_win<<<nbuck, 256, 0, stream>>>(BINNED, GCUR, RPD, CSRC, N);

    // ---- weight prep ----
    repack_all<<<560, 256, 0, stream>>>(W1, W2, mlpW, Wp1, Wp2, Wb);

    const int mblocks = (N + 127) / 128;   // 782
    const int gblocks = (int)(((long long)N * 64 + 255) / 256);

    // ---- layer 1 (reads fp32 x ONCE; PN written fp8) ----
    gemm1_mfma<<<mblocks, 512, 0, stream>>>(x, Wp1, PS, PN8, N);
    gather_combine<<<gblocks, 256, 0, stream>>>(PS, PN8, RPD, CSRC, H, N);

    // ---- layer 2 ----
    gemm2_mfma<<<mblocks, 512, 0, stream>>>(H, Wp2, PS, PN8, N);
    gather_combine<<<gblocks, 256, 0, stream>>>(PS, PN8, RPD, CSRC, H, N);

    // ---- head ----
    mlp_head_mfma<<<(N + 63) / 64, 256, 0, stream>>>(H, Wb, mlpb, (float*)d_out, N);
}

// Round 6
// 418.671 us; speedup vs baseline: 1.3530x; 1.0693x over previous
//
#include <hip/hip_runtime.h>
#include <hip/hip_bf16.h>

#define NFEAT 256
#define NHID  128
#define NCLASS 40

typedef __attribute__((ext_vector_type(8))) short short8;
typedef __attribute__((ext_vector_type(4))) float float4v;

__device__ __forceinline__ unsigned short f2bf(float f) {
    union { float f; unsigned u; } v; v.f = f;
    unsigned r = v.u + 0x7fff + ((v.u >> 16) & 1);   // RNE
    return (unsigned short)(r >> 16);
}
__device__ __forceinline__ float bflo(unsigned u) { return __uint_as_float(u << 16); }
__device__ __forceinline__ float bfhi(unsigned u) { return __uint_as_float(u & 0xffff0000u); }
// HW packed f32x2 -> bf16x2 (RNE), single VALU op; low half = a, high = b
__device__ __forceinline__ unsigned cvtpk_bf16(float a, float b) {
    unsigned r;
    asm("v_cvt_pk_bf16_f32 %0, %1, %2" : "=v"(r) : "v"(a), "v"(b));
    return r;
}

// async global->LDS, 16B per lane; LDS dest = wave-uniform base + lane*16
__device__ __forceinline__ void ld_g2l16(const unsigned short* gp, unsigned short* lp) {
    __builtin_amdgcn_global_load_lds((const __attribute__((address_space(1))) unsigned short*)gp,
                                     (__attribute__((address_space(3))) unsigned short*)lp,
                                     16, 0, 0);
}

#define TILE_E 4096   // edges per binning block
#define WCAP   20480  // padded slots per 512-row window (mean 16384, sigma~128 -> +32 sigma)

// ================= fused prep: bin_scatter blocks [0,nblk) + repack blocks [nblk,nblk+560) ====
// bin_scatter: tile histogram (regs-stashed) + per-bucket chunk reserve + scatter.
// packed entry: (row & 511) << 17 | col   (col < 2^17)
// Window w's edges land in binned[w*WCAP .. w*WCAP + gcur[w])  (padded, unordered)
// repack: W1,W2 -> K-panels [k0/32][o(256)][k(32)]; Wm -> padded bf16.
__global__ __launch_bounds__(256) void prep_fused(const int* __restrict__ rows,
                                                  const int* __restrict__ cols,
                                                  int* __restrict__ gcur,
                                                  unsigned* __restrict__ binned, int E, int nbuck,
                                                  int nblk,
                                                  const float* __restrict__ W1,
                                                  const float* __restrict__ W2,
                                                  const float* __restrict__ Wm,
                                                  unsigned short* __restrict__ Wp1,
                                                  unsigned short* __restrict__ Wp2,
                                                  unsigned short* __restrict__ Wb) {
    int t = threadIdx.x;
    if ((int)blockIdx.x >= nblk) {
        // ---- repack branch ----
        int b = blockIdx.x - nblk;
        if (b < 256) {                       // W1: o=b (0..255), k=t (0..255)
            float v = (b < 128) ? W1[b * 512 + t] : W1[(b - 128) * 512 + 256 + t];
            Wp1[(size_t)(t >> 5) * 256 * 32 + b * 32 + (t & 31)] = f2bf(v);
        } else if (b < 512) {                // W2: o=b-256 (0..255), k=t (0..127)
            int o = b - 256;
            if (t < 128) {
                float v = (o < 128) ? W2[o * 256 + t] : W2[(o - 128) * 256 + 128 + t];
                Wp2[(size_t)(t >> 5) * 256 * 32 + o * 32 + (t & 31)] = f2bf(v);
            }
        } else {                             // Wm: o=b-512 (0..47), k=t (0..127)
            int o = b - 512;
            if (t < 128) Wb[o * 128 + t] = (o < NCLASS) ? f2bf(Wm[o * 128 + t]) : 0;
        }
        return;
    }
    // ---- bin_scatter branch ----
    __shared__ int hh[256];
    __shared__ int lbase[256];
    __shared__ int lcur[256];
    hh[t] = 0;
    __syncthreads();
    int e0 = blockIdx.x * TILE_E;
    int4 rv[4];
    #pragma unroll
    for (int it = 0; it < TILE_E / 1024; ++it) {
        int base = e0 + (it * 256 + t) * 4;
        if (base + 3 < E) {
            rv[it] = *reinterpret_cast<const int4*>(&rows[base]);
            atomicAdd(&hh[rv[it].x >> 9], 1);
            atomicAdd(&hh[rv[it].y >> 9], 1);
            atomicAdd(&hh[rv[it].z >> 9], 1);
            atomicAdd(&hh[rv[it].w >> 9], 1);
        } else {
            for (int k = 0; k < 4; ++k)
                if (base + k < E) atomicAdd(&hh[rows[base + k] >> 9], 1);
        }
    }
    __syncthreads();
    if (t < nbuck) {
        int h = hh[t];
        lbase[t] = t * WCAP + (h ? atomicAdd(&gcur[t], h) : 0);
        lcur[t] = 0;
    }
    __syncthreads();
    #pragma unroll
    for (int it = 0; it < TILE_E / 1024; ++it) {
        int base = e0 + (it * 256 + t) * 4;
        if (base + 3 < E) {
            int4 r = rv[it];
            int4 c = *reinterpret_cast<const int4*>(&cols[base]);
            int b0 = r.x >> 9, b1 = r.y >> 9, b2 = r.z >> 9, b3 = r.w >> 9;
            int d0 = lbase[b0] + atomicAdd(&lcur[b0], 1);
            int d1 = lbase[b1] + atomicAdd(&lcur[b1], 1);
            int d2 = lbase[b2] + atomicAdd(&lcur[b2], 1);
            int d3 = lbase[b3] + atomicAdd(&lcur[b3], 1);
            binned[d0] = ((unsigned)(r.x & 511) << 17) | (unsigned)c.x;
            binned[d1] = ((unsigned)(r.y & 511) << 17) | (unsigned)c.y;
            binned[d2] = ((unsigned)(r.z & 511) << 17) | (unsigned)c.z;
            binned[d3] = ((unsigned)(r.w & 511) << 17) | (unsigned)c.w;
        } else {
            for (int k = 0; k < 4; ++k)
                if (base + k < E) {
                    int r = rows[base + k];
                    int b = r >> 9;
                    int dst = lbase[b] + atomicAdd(&lcur[b], 1);
                    binned[dst] = ((unsigned)(r & 511) << 17) | (unsigned)cols[base + k];
                }
        }
    }
}

// ======== fused layer-1: fill_win blocks [0,nfw) + gemm1 blocks [nfw,nfw+mblocks) =========
// fill_win (512-thr variant): one block per window: degrees+scan -> RPD{beg,deg,invdeg},
// ordered CSR cols. Scan phase uses t<256 guards with unconditional barriers (block-uniform).
// gemm1: [PS|PN8] = bf16(x[M x 256]) @ Wp1. BM=128, BN=256, 8 waves; A cvt via
// v_cvt_pk_bf16_f32, B via global_load_lds. PS bf16; PN fp8 e4m3 (halves gather bytes).
// LDS arena aliased: gemm1 sA(8K)+sB(16K)=24K; fill_win h(2K)+ps(1K)+lcur(2K)=5K.
__global__ __launch_bounds__(512) void gemm1_fw(const float* __restrict__ X,
                                                const unsigned short* __restrict__ Wp,
                                                unsigned short* __restrict__ PS,
                                                unsigned char* __restrict__ PN8,
                                                int M, int nfw,
                                                const unsigned* __restrict__ binned,
                                                const int* __restrict__ gcur,
                                                int4* __restrict__ rpd,
                                                int* __restrict__ csr_cols, int N) {
    __shared__ __align__(16) char smem[24576];
    const int t = threadIdx.x;

    if ((int)blockIdx.x < nfw) {
        // ---- fill_win branch (512 threads) ----
        int* h    = (int*)smem;          // 512
        int* ps   = h + 512;             // 256
        int* lcur = ps + 256;            // 512
        int w = blockIdx.x;
        int r0 = w << 9;
        h[t] = 0;
        if (t < 256) ps[t] = 0;
        __syncthreads();
        int beg = w * WCAP, end = beg + gcur[w];
        for (int e = beg + t; e < end; e += 512)
            atomicAdd(&h[binned[e] >> 17], 1);
        __syncthreads();
        int pair = 0;
        if (t < 256) { pair = h[2 * t] + h[2 * t + 1]; ps[t] = pair; }
        __syncthreads();
        for (int off = 1; off < 256; off <<= 1) {
            int tmp = (t >= off && t < 256) ? ps[t - off] : 0;
            __syncthreads();
            if (t < 256) ps[t] += tmp;
            __syncthreads();
        }
        if (t < 256) {
            int base0 = beg + ps[t] - pair;
            int base1 = base0 + h[2 * t];
            int r_a = r0 + 2 * t, r_b = r0 + 2 * t + 1;
            if (r_a < N) {
                int4 m; m.x = base0; m.y = h[2 * t];
                m.z = __float_as_int(1.0f / ((float)h[2 * t] + 1.0f)); m.w = 0;
                rpd[r_a] = m;
            }
            if (r_b < N) {
                int4 m; m.x = base1; m.y = h[2 * t + 1];
                m.z = __float_as_int(1.0f / ((float)h[2 * t + 1] + 1.0f)); m.w = 0;
                rpd[r_b] = m;
            }
            lcur[2 * t] = base0;
            lcur[2 * t + 1] = base1;
        }
        __syncthreads();
        for (int e = beg + t; e < end; e += 512) {
            unsigned v = binned[e];
            int idx = atomicAdd(&lcur[v >> 17], 1);
            csr_cols[idx] = (int)(v & 0x1FFFFu);
        }
        return;
    }

    // ---- gemm1 branch ----
    unsigned short* sA = (unsigned short*)smem;            // 128*32 bf16 = 8 KB
    unsigned short* sB = (unsigned short*)(smem + 8192);   // 256*32 bf16 = 16 KB
    const int lane = t & 63;
    const int wave = t >> 6;              // 0..7
    const int m0 = (blockIdx.x - nfw) * 128;
    const int wm = (wave >> 2) * 64;      // 0 or 64
    const int wn = (wave & 3) * 64;       // 0,64,128,192

    const int r15 = lane & 15;
    const int k8  = (lane >> 4) * 8;
    const int arow = t >> 2;              // 0..127
    const int ac8  = (t & 3) * 8;
    const int brow = lane >> 2;           // 0..15
    const int bc8  = (lane & 3) * 8;

    float4v acc[4][4] = {{{0.f,0.f,0.f,0.f}}};
    const int gm = min(m0 + arow, M - 1);        // clamp: x is an input alloc
    const float* gA = X + (size_t)gm * 256 + ac8;

    for (int k0 = 0; k0 < 256; k0 += 32) {
        const unsigned short* pan = Wp + (size_t)(k0 >> 5) * 256 * 32;
        float4 v0 = *reinterpret_cast<const float4*>(gA + k0);
        float4 v1 = *reinterpret_cast<const float4*>(gA + k0 + 4);
        uint4 q;
        q.x = cvtpk_bf16(v0.x, v0.y);
        q.y = cvtpk_bf16(v0.z, v0.w);
        q.z = cvtpk_bf16(v1.x, v1.y);
        q.w = cvtpk_bf16(v1.z, v1.w);
        *reinterpret_cast<uint4*>(&sA[arow * 32 + ac8]) = q;
        #pragma unroll
        for (int it = 0; it < 2; ++it) {
            int slab = it * 128 + wave * 16;
            ld_g2l16(pan + (size_t)(slab + brow) * 32 + bc8, &sB[slab * 32]);
        }
        __syncthreads();

        short8 aF[4], bF[4];
        #pragma unroll
        for (int i = 0; i < 4; ++i)
            aF[i] = *reinterpret_cast<const short8*>(&sA[(wm + i * 16 + r15) * 32 + k8]);
        #pragma unroll
        for (int j = 0; j < 4; ++j)
            bF[j] = *reinterpret_cast<const short8*>(&sB[(wn + j * 16 + r15) * 32 + k8]);
        #pragma unroll
        for (int i = 0; i < 4; ++i)
            #pragma unroll
            for (int j = 0; j < 4; ++j)
                acc[i][j] = __builtin_amdgcn_mfma_f32_16x16x32_bf16(aF[i], bF[j], acc[i][j], 0, 0, 0);
        __syncthreads();
    }

    #pragma unroll
    for (int i = 0; i < 4; ++i) {
        #pragma unroll
        for (int r = 0; r < 4; ++r) {
            int row = m0 + wm + i * 16 + (lane >> 4) * 4 + r;
            #pragma unroll
            for (int j = 0; j < 4; ++j) {
                float v  = acc[i][j][r];
                float vn = __shfl_xor(v, 1);
                int cN = wn + j * 16 + r15;
                if (row < M && !(r15 & 1)) {
                    if (cN < 128) {
                        *reinterpret_cast<unsigned*>(&PS[(size_t)row * 128 + cN]) = cvtpk_bf16(v, vn);
                    } else {
                        unsigned p8 = __builtin_amdgcn_cvt_pk_fp8_f32(v, vn, 0u, false);
                        *reinterpret_cast<unsigned short*>(&PN8[(size_t)row * 128 + (cN - 128)]) =
                            (unsigned short)p8;
                    }
                }
            }
        }
    }
}

// ---------------- layer-2 GEMM: [PS|PN8] = H[M x 128] @ Wp2, async A+B staging ----------------
// BM=128, BN=256 (one pass over H). A-tail of last M-block overreads into adjacent ws — safe.
__global__ __launch_bounds__(512) void gemm2_mfma(const unsigned short* __restrict__ H,
                                                  const unsigned short* __restrict__ Wp,
                                                  unsigned short* __restrict__ PS,
                                                  unsigned char* __restrict__ PN8,
                                                  int M) {
    __shared__ unsigned short sA[128 * 32];
    __shared__ unsigned short sB[256 * 32];
    const int t    = threadIdx.x;
    const int lane = t & 63;
    const int wave = t >> 6;
    const int m0 = blockIdx.x * 128;
    const int wm = (wave >> 2) * 64;
    const int wn = (wave & 3) * 64;

    const int r15 = lane & 15;
    const int k8  = (lane >> 4) * 8;
    const int brow = lane >> 2;
    const int bc8  = (lane & 3) * 8;

    float4v acc[4][4] = {{{0.f,0.f,0.f,0.f}}};

    for (int k0 = 0; k0 < 128; k0 += 32) {
        const unsigned short* pan = Wp + (size_t)(k0 >> 5) * 256 * 32;
        int slabA = wave * 16;
        ld_g2l16(H + (size_t)(m0 + slabA + brow) * 128 + k0 + bc8, &sA[slabA * 32]);
        #pragma unroll
        for (int it = 0; it < 2; ++it) {
            int slab = it * 128 + wave * 16;
            ld_g2l16(pan + (size_t)(slab + brow) * 32 + bc8, &sB[slab * 32]);
        }
        __syncthreads();

        short8 aF[4], bF[4];
        #pragma unroll
        for (int i = 0; i < 4; ++i)
            aF[i] = *reinterpret_cast<const short8*>(&sA[(wm + i * 16 + r15) * 32 + k8]);
        #pragma unroll
        for (int j = 0; j < 4; ++j)
            bF[j] = *reinterpret_cast<const short8*>(&sB[(wn + j * 16 + r15) * 32 + k8]);
        #pragma unroll
        for (int i = 0; i < 4; ++i)
            #pragma unroll
            for (int j = 0; j < 4; ++j)
                acc[i][j] = __builtin_amdgcn_mfma_f32_16x16x32_bf16(aF[i], bF[j], acc[i][j], 0, 0, 0);
        __syncthreads();
    }

    #pragma unroll
    for (int i = 0; i < 4; ++i) {
        #pragma unroll
        for (int r = 0; r < 4; ++r) {
            int row = m0 + wm + i * 16 + (lane >> 4) * 4 + r;
            #pragma unroll
            for (int j = 0; j < 4; ++j) {
                float v  = acc[i][j][r];
                float vn = __shfl_xor(v, 1);
                int cN = wn + j * 16 + r15;
                if (row < M && !(r15 & 1)) {
                    if (cN < 128) {
                        *reinterpret_cast<unsigned*>(&PS[(size_t)row * 128 + cN]) = cvtpk_bf16(v, vn);
                    } else {
                        unsigned p8 = __builtin_amdgcn_cvt_pk_fp8_f32(v, vn, 0u, false);
                        *reinterpret_cast<unsigned short*>(&PN8[(size_t)row * 128 + (cN - 128)]) =
                            (unsigned short)p8;
                    }
                }
            }
        }
    }
}

// fp8x8 (one uint2) -> 8 f32 accumulate via HW v_cvt_pk_f32_fp8
__device__ __forceinline__ void acc_fp8x8(uint2 u,
                                          float& a0, float& a1, float& a2, float& a3,
                                          float& a4, float& a5, float& a6, float& a7) {
    auto f01 = __builtin_amdgcn_cvt_pk_f32_fp8(u.x, false);
    auto f23 = __builtin_amdgcn_cvt_pk_f32_fp8(u.x, true);
    auto f45 = __builtin_amdgcn_cvt_pk_f32_fp8(u.y, false);
    auto f67 = __builtin_amdgcn_cvt_pk_f32_fp8(u.y, true);
    a0 += f01[0]; a1 += f01[1]; a2 += f23[0]; a3 += f23[1];
    a4 += f45[0]; a5 += f45[1]; a6 += f67[0]; a7 += f67[1];
}

// ---------------- gather-aggregate + combine + relu: one wave per node ----------------
// PN fp8: 128B/row random working set 12.8MB. Node metadata (beg,deg,invdeg) in one int4.
__global__ __launch_bounds__(256) void gather_combine(const unsigned short* __restrict__ PS,
                                                      const unsigned char* __restrict__ PN8,
                                                      const int4* __restrict__ rpd,
                                                      const int* __restrict__ csr_cols,
                                                      unsigned short* __restrict__ H, int N) {
    int node = (blockIdx.x * blockDim.x + threadIdx.x) >> 6;
    if (node >= N) return;
    int lane = threadIdx.x & 63;
    int grp  = lane >> 4;
    int l16  = lane & 15;
    int4 md = rpd[node];
    int beg = md.x, end = md.x + md.y;
    float id = __int_as_float(md.z);

    uint4 us = {0u, 0u, 0u, 0u};
    if (grp == 0)
        us = *reinterpret_cast<const uint4*>(&PS[(size_t)node * 128 + l16 * 8]);

    float a0=0,a1=0,a2=0,a3=0,a4=0,a5=0,a6=0,a7=0;
    int p0 = beg + grp;
    for (; p0 + 12 < end; p0 += 16) {
        int cA = csr_cols[p0];
        int cB = csr_cols[p0 + 4];
        int cC = csr_cols[p0 + 8];
        int cD = csr_cols[p0 + 12];
        uint2 uA = *reinterpret_cast<const uint2*>(&PN8[(size_t)cA * 128 + l16 * 8]);
        uint2 uB = *reinterpret_cast<const uint2*>(&PN8[(size_t)cB * 128 + l16 * 8]);
        uint2 uC = *reinterpret_cast<const uint2*>(&PN8[(size_t)cC * 128 + l16 * 8]);
        uint2 uD = *reinterpret_cast<const uint2*>(&PN8[(size_t)cD * 128 + l16 * 8]);
        acc_fp8x8(uA, a0, a1, a2, a3, a4, a5, a6, a7);
        acc_fp8x8(uB, a0, a1, a2, a3, a4, a5, a6, a7);
        acc_fp8x8(uC, a0, a1, a2, a3, a4, a5, a6, a7);
        acc_fp8x8(uD, a0, a1, a2, a3, a4, a5, a6, a7);
    }
    for (; p0 < end; p0 += 4) {
        int c = csr_cols[p0];
        uint2 u = *reinterpret_cast<const uint2*>(&PN8[(size_t)c * 128 + l16 * 8]);
        acc_fp8x8(u, a0, a1, a2, a3, a4, a5, a6, a7);
    }
    a0 += __shfl_xor(a0, 16); a1 += __shfl_xor(a1, 16);
    a2 += __shfl_xor(a2, 16); a3 += __shfl_xor(a3, 16);
    a4 += __shfl_xor(a4, 16); a5 += __shfl_xor(a5, 16);
    a6 += __shfl_xor(a6, 16); a7 += __shfl_xor(a7, 16);
    a0 += __shfl_xor(a0, 32); a1 += __shfl_xor(a1, 32);
    a2 += __shfl_xor(a2, 32); a3 += __shfl_xor(a3, 32);
    a4 += __shfl_xor(a4, 32); a5 += __shfl_xor(a5, 32);
    a6 += __shfl_xor(a6, 32); a7 += __shfl_xor(a7, 32);

    if (grp == 0) {
        float h0 = fmaxf(fmaf(a0, id, bflo(us.x)), 0.f);
        float h1 = fmaxf(fmaf(a1, id, bfhi(us.x)), 0.f);
        float h2 = fmaxf(fmaf(a2, id, bflo(us.y)), 0.f);
        float h3 = fmaxf(fmaf(a3, id, bfhi(us.y)), 0.f);
        float h4 = fmaxf(fmaf(a4, id, bflo(us.z)), 0.f);
        float h5 = fmaxf(fmaf(a5, id, bfhi(us.z)), 0.f);
        float h6 = fmaxf(fmaf(a6, id, bflo(us.w)), 0.f);
        float h7 = fmaxf(fmaf(a7, id, bfhi(us.w)), 0.f);
        uint4 o;
        o.x = cvtpk_bf16(h0, h1); o.y = cvtpk_bf16(h2, h3);
        o.z = cvtpk_bf16(h4, h5); o.w = cvtpk_bf16(h6, h7);
        *reinterpret_cast<uint4*>(&H[(size_t)node * 128 + l16 * 8]) = o;
    }
}

// ---------------- MFMA head: logits = H @ Wb^T (+bias), fused log_softmax ----------------
__global__ __launch_bounds__(256) void mlp_head_mfma(const unsigned short* __restrict__ H,
                                                     const unsigned short* __restrict__ Wb,
                                                     const float* __restrict__ bm,
                                                     float* __restrict__ out, int N) {
    __shared__ unsigned short sW[48 * 128];   // 12 KB
    int t = threadIdx.x;
    for (int i = t; i < 48 * 128 / 2; i += 256)
        ((unsigned*)sW)[i] = ((const unsigned*)Wb)[i];
    __syncthreads();

    const int wave = t >> 6, lane = t & 63;
    const int m0 = blockIdx.x * 64 + wave * 16;
    if (m0 >= N) return;
    const int r15 = lane & 15;
    const int k8  = (lane >> 4) * 8;
    const int arow = min(m0 + r15, N - 1);

    float4v acc[3] = {{0.f,0.f,0.f,0.f},{0.f,0.f,0.f,0.f},{0.f,0.f,0.f,0.f}};
    #pragma unroll
    for (int k0 = 0; k0 < 128; k0 += 32) {
        short8 a = *reinterpret_cast<const short8*>(&H[(size_t)arow * 128 + k0 + k8]);
        #pragma unroll
        for (int f = 0; f < 3; ++f) {
            short8 b = *reinterpret_cast<const short8*>(&sW[(f * 16 + r15) * 128 + k0 + k8]);
            acc[f] = __builtin_amdgcn_mfma_f32_16x16x32_bf16(a, b, acc[f], 0, 0, 0);
        }
    }

    float bias[3]; bool cv[3];
    #pragma unroll
    for (int f = 0; f < 3; ++f) {
        int c = f * 16 + r15;
        cv[f] = (c < NCLASS);
        bias[f] = cv[f] ? bm[c] : 0.f;
    }
    #pragma unroll
    for (int r = 0; r < 4; ++r) {
        int node = m0 + (lane >> 4) * 4 + r;
        float lg[3];
        float m = -1e30f;
        #pragma unroll
        for (int f = 0; f < 3; ++f) {
            lg[f] = cv[f] ? (acc[f][r] + bias[f]) : -1e30f;
            m = fmaxf(m, lg[f]);
        }
        m = fmaxf(m, __shfl_xor(m, 1));
        m = fmaxf(m, __shfl_xor(m, 2));
        m = fmaxf(m, __shfl_xor(m, 4));
        m = fmaxf(m, __shfl_xor(m, 8));
        float s = 0.f;
        #pragma unroll
        for (int f = 0; f < 3; ++f) s += cv[f] ? __expf(lg[f] - m) : 0.f;
        s += __shfl_xor(s, 1);
        s += __shfl_xor(s, 2);
        s += __shfl_xor(s, 4);
        s += __shfl_xor(s, 8);
        float ls = __logf(s);
        if (node < N) {
            #pragma unroll
            for (int f = 0; f < 3; ++f)
                if (cv[f]) out[(size_t)node * NCLASS + f * 16 + r15] = lg[f] - m - ls;
        }
    }
}

extern "C" void kernel_launch(void* const* d_in, const int* in_sizes, int n_in,
                              void* d_out, int out_size, void* d_ws, size_t ws_size,
                              hipStream_t stream) {
    const float* x    = (const float*)d_in[0];
    const float* W1   = (const float*)d_in[1];
    const float* W2   = (const float*)d_in[2];
    const float* mlpW = (const float*)d_in[3];
    const float* mlpb = (const float*)d_in[4];
    const int*   rows = (const int*)d_in[5];
    const int*   cols = (const int*)d_in[6];

    const int N = in_sizes[0] / NFEAT;   // 100000
    const int E = in_sizes[5];           // 3200000

    char* ws = (char*)d_ws;
    size_t off = 0;
    auto alloc = [&](size_t bytes) -> void* {
        void* p = ws + off;
        off = (off + bytes + 255) & ~(size_t)255;
        return p;
    };
    const int nbuck = (N + 511) >> 9;              // 196
    const int nblk  = (E + TILE_E - 1) / TILE_E;   // 782

    unsigned short* PS  = (unsigned short*)alloc((size_t)N * 128 * 2);  // self-projection (bf16)
    unsigned char*  PN8 = (unsigned char*) alloc((size_t)N * 128);      // neigh-projection (fp8 e4m3)
    unsigned short* H   = (unsigned short*)alloc((size_t)N * 128 * 2);  // hidden (bf16)
    int4*  RPD    = (int4*) alloc((size_t)N * 16);                      // {beg, deg, invdeg, 0}
    int*   CSRC   = (int*)  alloc((size_t)nbuck * WCAP * 4);            // padded CSR cols
    unsigned* BINNED = (unsigned*)alloc((size_t)nbuck * WCAP * 4);      // padded window bins
    int*   GCUR   = (int*)  alloc((size_t)256 * 4);
    unsigned short* Wp1 = (unsigned short*)alloc((size_t)256 * 256 * 2);
    unsigned short* Wp2 = (unsigned short*)alloc((size_t)128 * 256 * 2);
    unsigned short* Wb  = (unsigned short*)alloc((size_t)48 * 128 * 2);

    const int mblocks = (N + 127) / 128;   // 782
    const int gblocks = (int)(((long long)N * 64 + 255) / 256);

    // ---- launch 1+2: CSR scatter + weight repack (independent, co-scheduled) ----
    hipMemsetAsync(GCUR, 0, 256 * 4, stream);
    prep_fused<<<nblk + 560, 256, 0, stream>>>(rows, cols, GCUR, BINNED, E, nbuck, nblk,
                                               W1, W2, mlpW, Wp1, Wp2, Wb);

    // ---- launch 3: fill_win (needs scatter) || gemm1 (needs repack) — independent ----
    // fill_win blocks first so they're resident immediately alongside early gemm1 blocks.
    gemm1_fw<<<nbuck + mblocks, 512, 0, stream>>>(x, Wp1, PS, PN8, N, nbuck,
                                                  BINNED, GCUR, RPD, CSRC, N);
    gather_combine<<<gblocks, 256, 0, stream>>>(PS, PN8, RPD, CSRC, H, N);

    // ---- layer 2 ----
    gemm2_mfma<<<mblocks, 512, 0, stream>>>(H, Wp2, PS, PN8, N);
    gather_combine<<<gblocks, 256, 0, stream>>>(PS, PN8, RPD, CSRC, H, N);

    // ---- head ----
    mlp_head_mfma<<<(N + 63) / 64, 256, 0, stream>>>(H, Wb, mlpb, (float*)d_out, N);
}